// Round 13
// baseline (1218.828 us; speedup 1.0000x reference)
//
#include <hip/hip_runtime.h>
#include <hip/hip_fp16.h>
#include <math.h>

// ---------------- constants ----------------
constexpr int   N_   = 2048;
constexpr int   DF_  = 256;
constexpr int   J_   = 8;
constexpr int   ELLW_= 64;
constexpr int   M_   = 256;          // coefficient array stride (256-pt DCT quadrature)
constexpr int   MUSE_= 48;           // Chebyshev terms actually used (degree 47)
constexpr int   GCAP_= 12;           // ring 101MB; exactly 4 reduce passes (12x4)
constexpr float H_   = 1.01f;        // domain half-width  ([-0.01, 2.01])
constexpr float C0_  = 1.0f;         // domain center
constexpr float AF_  = 0.34657359027997264f;   // A = 3*ln(2)/6
constexpr float PI_F = 3.14159265358979323846f;

typedef _Float16 f16x8 __attribute__((ext_vector_type(8)));
typedef __attribute__((ext_vector_type(4))) float f32x4;
using u16 = unsigned short;

// ---------------- filter functions ----------------
__device__ __forceinline__ float g_hat_f(float x) {
    float val = 0.5f + 0.5f * cosf(2.f * PI_F * (x / AF_ + 0.5f));
    return (x <= 0.f && x > -AF_) ? val : 0.f;
}
__device__ __forceinline__ float wavelet_f(float lamb, int j) {
    float lmin = expf(AF_ * ((j - 1) / 3.0f - 1.0f));
    float lam  = fmaxf(lamb, lmin);
    return g_hat_f(logf(lam) - AF_ * (j - 1) / 3.0f);
}
__device__ __forceinline__ float filter_eval(float lamb, int jf) {
    if (jf == 0) {
        float g3 = 0.f;
        for (int j = 2; j <= 8; ++j) { float w = wavelet_f(lamb, j); g3 += w * w; }
        return sqrtf(fmaxf(1.5f - g3, 0.f));
    }
    return wavelet_f(lamb, jf + 1);
}

// ---------------- setup kernels ----------------
__global__ __launch_bounds__(256) void deg_kernel(const float* __restrict__ W,
                                                  float* __restrict__ dh,
                                                  float* __restrict__ dr) {
    int i = blockIdx.x, t = threadIdx.x;
    const float4* row = (const float4*)(W + (size_t)i * N_);
    float s = 0.f;
    for (int c = t; c < N_ / 4; c += 256) { float4 v = row[c]; s += v.x + v.y + v.z + v.w; }
    __shared__ float red[256];
    red[t] = s; __syncthreads();
    for (int o = 128; o; o >>= 1) { if (t < o) red[t] += red[t + o]; __syncthreads(); }
    if (t == 0) {
        float deg = red[0];
        float dhi = 1.f / sqrtf(fmaxf(deg, 1.f));
        dh[i] = dhi;
        dr[i] = (dhi * dhi * deg - C0_) / H_;
    }
}

// ELL build: all 64 entries pre-filled with (col=i, val=0) pads; cnt rounded up to mult of 8.
__global__ __launch_bounds__(64) void ell_kernel(const float* __restrict__ W,
                                                 const float* __restrict__ dh,
                                                 int* __restrict__ cnt,
                                                 int* __restrict__ cols,
                                                 float* __restrict__ vals) {
    int i = blockIdx.x, lane = threadIdx.x;
    cols[i * ELLW_ + lane] = i;            // pad defaults
    vals[i * ELLW_ + lane] = 0.f;
    __syncthreads();
    const float* row = W + (size_t)i * N_;
    unsigned long long lt = (1ull << lane) - 1ull;
    int base = 0;
    float dhi = dh[i];
    for (int c = 0; c < N_; c += 64) {
        float v = row[c + lane];
        unsigned long long m = __ballot(v != 0.f);
        if (v != 0.f) {
            int pos = base + __popcll(m & lt);
            if (pos < ELLW_) {
                cols[i * ELLW_ + pos] = c + lane;
                vals[i * ELLW_ + pos] = dhi * dh[c + lane] / H_;
            }
        }
        base += __popcll(m);
    }
    if (lane == 0) {
        int n = base < ELLW_ ? base : ELLW_;
        cnt[i] = (n + 7) & ~7;             // padded count (pads are no-ops)
    }
}

// deterministic counting sort of rows by padded degree -> perm (parallel scan version)
__global__ __launch_bounds__(256) void perm_kernel(const int* __restrict__ cnt,
                                                   int* __restrict__ perm) {
    __shared__ int hist[9][256];           // per-thread bucket counts -> exclusive offsets
    __shared__ int bstart[9];
    int t = threadIdx.x;
    int b[8];
    int h[9] = {0, 0, 0, 0, 0, 0, 0, 0, 0};
#pragma unroll
    for (int u = 0; u < 8; ++u) {
        b[u] = cnt[t * 8 + u] >> 3;        // bucket 0..8
        h[b[u]]++;
    }
#pragma unroll
    for (int bb = 0; bb < 9; ++bb) hist[bb][t] = h[bb];
    __syncthreads();
    if (t < 9) {                           // exclusive scan across threads, per bucket
        int acc = 0;
        for (int k = 0; k < 256; ++k) { int v = hist[t][k]; hist[t][k] = acc; acc += v; }
        bstart[t] = acc;                   // bucket total
    }
    __syncthreads();
    if (t == 0) {                          // exclusive scan of bucket totals
        int acc = 0;
        for (int bb = 0; bb < 9; ++bb) { int v = bstart[bb]; bstart[bb] = acc; acc += v; }
    }
    __syncthreads();
    int run[9] = {0, 0, 0, 0, 0, 0, 0, 0, 0};
#pragma unroll
    for (int u = 0; u < 8; ++u) {
        int bb = b[u];
        perm[bstart[bb] + hist[bb][t] + run[bb]] = t * 8 + u;
        run[bb]++;
    }
}

// parallel DCT: 64 blocks = 8 filters x 8 output-chunks; 8 threads per output.
__global__ __launch_bounds__(256) void coef_kernel(float* __restrict__ coefs) {
    __shared__ float fv[M_];
    int j     = blockIdx.x >> 3;
    int chunk = blockIdx.x & 7;
    int t = threadIdx.x;
    float theta = PI_F * (t + 0.5f) / M_;
    fv[t] = filter_eval(C0_ + H_ * cosf(theta), j);
    __syncthreads();
    int out = chunk * 32 + (t >> 3);       // output index 0..255
    int seg = t & 7;                       // 8 threads per output
    float s = 0.f;
    for (int i = seg * 32; i < seg * 32 + 32; ++i)
        s += fv[i] * cosf(PI_F * out * (i + 0.5f) / M_);
    s += __shfl_xor(s, 1);
    s += __shfl_xor(s, 2);
    s += __shfl_xor(s, 4);
    if (seg == 0) coefs[j * M_ + out] = s * ((out == 0 ? 1.f : 2.f) / M_);
}

// slot0 = I (fp16), slot1 = scaled L-tilde (fp16)
__global__ __launch_bounds__(256) void init_slots(__half* __restrict__ S0, __half* __restrict__ S1,
                                                  const int* __restrict__ cnt, const int* __restrict__ cols,
                                                  const float* __restrict__ vals, const float* __restrict__ dr) {
    int i = blockIdx.x, t = threadIdx.x;
    size_t ro = (size_t)i * N_;
    for (int c = t * 8; c < N_; c += 2048) {
        *(uint4*)(S0 + ro + c) = uint4{0, 0, 0, 0};
        *(uint4*)(S1 + ro + c) = uint4{0, 0, 0, 0};
    }
    __syncthreads();
    int n = cnt[i];
    if (t < n) {
        int c = cols[i * ELLW_ + t];
        float v = -vals[i * ELLW_ + t];
        if (v != 0.f) S1[ro + c] = __float2half(v);   // skip pads (col=i, val=0)
    }
    __syncthreads();
    if (t == 0) {
        S0[ro + i] = __float2half(1.f);
        S1[ro + i] = __float2half(dr[i]);
    }
}

// ------- Chebyshev step, XCD-striped + degree-sorted rows (proven R8 form: unroll-8) -----
__global__ __launch_bounds__(256) void cheb_fp16(const __half* __restrict__ X,
                                                 const __half* __restrict__ Tprev,
                                                 __half* __restrict__ Tnext,
                                                 const int* __restrict__ cnt,
                                                 const int* __restrict__ cols,
                                                 const float* __restrict__ vals,
                                                 const float* __restrict__ dr,
                                                 const int* __restrict__ perm) {
    int strp = blockIdx.x & 7;
    int rg   = blockIdx.x >> 3;
    int tr   = threadIdx.x >> 5;           // 0..7: row within block
    int lr   = threadIdx.x & 31;
    __shared__ int   sperm[8];
    __shared__ int   scnt[8];
    __shared__ int   scols[8][ELLW_];
    __shared__ float svals[8][ELLW_];
    if (threadIdx.x < 8) {
        int p = perm[rg * 8 + threadIdx.x];
        sperm[threadIdx.x] = p;
        scnt[threadIdx.x]  = cnt[p];
    }
    __syncthreads();
    {
        int e = threadIdx.x & 63, r0 = threadIdx.x >> 6;      // r0 in 0..3
        int p0 = sperm[r0], p1 = sperm[r0 + 4];
        scols[r0][e] = cols[p0 * ELLW_ + e];     svals[r0][e] = vals[p0 * ELLW_ + e];
        scols[r0 + 4][e] = cols[p1 * ELLW_ + e]; svals[r0 + 4][e] = vals[p1 * ELLW_ + e];
    }
    __syncthreads();
    int i   = sperm[tr];
    int n   = scnt[tr];                      // multiple of 8 (or 0)
    int col = strp * 256 + lr * 8;
    float a[8] = {0, 0, 0, 0, 0, 0, 0, 0};
    for (int e0 = 0; e0 < n; e0 += 8) {
        uint4 q[8];
        float v[8];
#pragma unroll
        for (int u = 0; u < 8; ++u) {
            int c = scols[tr][e0 + u];
            v[u] = svals[tr][e0 + u];
            q[u] = *(const uint4*)(X + (size_t)c * N_ + col);
        }
#pragma unroll
        for (int u = 0; u < 8; ++u) {
            const __half2* h = (const __half2*)&q[u];
            float2 f0 = __half22float2(h[0]), f1 = __half22float2(h[1]);
            float2 f2 = __half22float2(h[2]), f3 = __half22float2(h[3]);
            a[0] -= v[u] * f0.x; a[1] -= v[u] * f0.y;
            a[2] -= v[u] * f1.x; a[3] -= v[u] * f1.y;
            a[4] -= v[u] * f2.x; a[5] -= v[u] * f2.y;
            a[6] -= v[u] * f3.x; a[7] -= v[u] * f3.y;
        }
    }
    size_t po = (size_t)i * N_ + col;
    {   // diagonal term
        float d = dr[i];
        uint4 q = *(const uint4*)(X + po);
        const __half2* h = (const __half2*)&q;
        float2 f0 = __half22float2(h[0]), f1 = __half22float2(h[1]);
        float2 f2 = __half22float2(h[2]), f3 = __half22float2(h[3]);
        a[0] += d * f0.x; a[1] += d * f0.y; a[2] += d * f1.x; a[3] += d * f1.y;
        a[4] += d * f2.x; a[5] += d * f2.y; a[6] += d * f3.x; a[7] += d * f3.y;
    }
    uint4 qp = *(const uint4*)(Tprev + po);
    const __half2* hp = (const __half2*)&qp;
    float2 p0 = __half22float2(hp[0]), p1 = __half22float2(hp[1]);
    float2 p2 = __half22float2(hp[2]), p3 = __half22float2(hp[3]);
    __half2 s0 = __floats2half2_rn(2.f * a[0] - p0.x, 2.f * a[1] - p0.y);
    __half2 s1 = __floats2half2_rn(2.f * a[2] - p1.x, 2.f * a[3] - p1.y);
    __half2 s2 = __floats2half2_rn(2.f * a[4] - p2.x, 2.f * a[5] - p2.y);
    __half2 s3 = __floats2half2_rn(2.f * a[6] - p3.x, 2.f * a[7] - p3.y);
    uint4 sq;
    sq.x = *(const unsigned int*)&s0; sq.y = *(const unsigned int*)&s1;
    sq.z = *(const unsigned int*)&s2; sq.w = *(const unsigned int*)&s3;
    *(uint4*)(Tnext + po) = sq;
}

// ---------------- group reduction: Gh_j += sum_{k in [k0,k0+nslot)} b_{jk} * slot(k%g) -------
__global__ __launch_bounds__(256) void reduce_half(const __half* __restrict__ slots,
                                                   int g, int k0, int nslot, int initG,
                                                   const float* __restrict__ coefs,
                                                   __half* __restrict__ Gh) {
    const size_t NSQ = (size_t)N_ * N_;
    size_t idx = ((size_t)blockIdx.x * 256 + threadIdx.x) * 8;
    __shared__ float sc[J_ * 64];
    for (int x = threadIdx.x; x < J_ * nslot; x += 256) {
        int j = x / nslot, s = x - j * nslot;
        sc[j * 64 + s] = coefs[j * M_ + k0 + s];
    }
    __syncthreads();
    float acc[J_][8];
#pragma unroll
    for (int j = 0; j < J_; ++j) {
        if (initG) {
#pragma unroll
            for (int r = 0; r < 8; ++r) acc[j][r] = 0.f;
        } else {
            uint4 q = *(const uint4*)(Gh + (size_t)j * NSQ + idx);
            const __half2* h = (const __half2*)&q;
            float2 f0 = __half22float2(h[0]), f1 = __half22float2(h[1]);
            float2 f2 = __half22float2(h[2]), f3 = __half22float2(h[3]);
            acc[j][0] = f0.x; acc[j][1] = f0.y; acc[j][2] = f1.x; acc[j][3] = f1.y;
            acc[j][4] = f2.x; acc[j][5] = f2.y; acc[j][6] = f3.x; acc[j][7] = f3.y;
        }
    }
    for (int s = 0; s < nslot; ++s) {
        int slot = (k0 + s) % g;
        uint4 q = *(const uint4*)(slots + (size_t)slot * NSQ + idx);
        const __half2* h = (const __half2*)&q;
        float2 f0 = __half22float2(h[0]), f1 = __half22float2(h[1]);
        float2 f2 = __half22float2(h[2]), f3 = __half22float2(h[3]);
        float f[8] = {f0.x, f0.y, f1.x, f1.y, f2.x, f2.y, f3.x, f3.y};
#pragma unroll
        for (int j = 0; j < J_; ++j) {
            float c = sc[j * 64 + s];
#pragma unroll
            for (int r = 0; r < 8; ++r) acc[j][r] += c * f[r];
        }
    }
#pragma unroll
    for (int j = 0; j < J_; ++j) {
        __half2 o0 = __floats2half2_rn(acc[j][0], acc[j][1]);
        __half2 o1 = __floats2half2_rn(acc[j][2], acc[j][3]);
        __half2 o2 = __floats2half2_rn(acc[j][4], acc[j][5]);
        __half2 o3 = __floats2half2_rn(acc[j][6], acc[j][7]);
        uint4 o;
        o.x = *(const unsigned int*)&o0; o.y = *(const unsigned int*)&o1;
        o.z = *(const unsigned int*)&o2; o.w = *(const unsigned int*)&o3;
        *(uint4*)(Gh + (size_t)j * NSQ + idx) = o;
    }
}

// ---------------- f [2048][256] f32  ->  fhT [256][2048] f16 (transposed) ----------------
__global__ __launch_bounds__(256) void transpose_f16(const float* __restrict__ src,
                                                     __half* __restrict__ dst) {
    int d = blockIdx.x;                    // 256 output rows
    int i0 = threadIdx.x * 8;              // 8 nodes per thread
    __half h[8];
#pragma unroll
    for (int u = 0; u < 8; ++u) h[u] = __float2half(src[(size_t)(i0 + u) * DF_ + d]);
    uint4 o;
    __half2* hp = (__half2*)&o;
    hp[0] = __half2{h[0], h[1]}; hp[1] = __half2{h[2], h[3]};
    hp[2] = __half2{h[4], h[5]}; hp[3] = __half2{h[6], h[7]};
    *(uint4*)(dst + (size_t)d * N_ + i0) = o;
}

// ---------------- MODE-0 MFMA GEMM (128x128): U1T = |Gh * fhT^T|, colsum1 ----------------
// 1D grid 256, XCD-chunked: xcd = bid&7 owns m-chunk [xcd*16, xcd*16+16) x 2 n-tiles.
__global__ __launch_bounds__(256) void mfma_gemm0(const __half* __restrict__ A,
                                                  const __half* __restrict__ BT,
                                                  __half* __restrict__ U1T,
                                                  float* __restrict__ colsum) {
    __shared__ u16 As[128 * 64];
    __shared__ u16 Bs[128 * 64];
    int bid = blockIdx.x;
    int xcd = bid & 7, t2 = bid >> 3;      // t2 in 0..31
    int mt  = xcd * 16 + (t2 >> 1);        // m-tile 0..127
    int nt  = t2 & 1;                      // n-tile 0..1
    int tid = threadIdx.x;
    int w = tid >> 6, lane = tid & 63;
    int wr = w >> 1, wc = w & 1;
    int gm0 = mt * 128, n0 = nt * 128;
    f32x4 acc[4][4];
#pragma unroll
    for (int mf = 0; mf < 4; ++mf)
#pragma unroll
        for (int nf = 0; nf < 4; ++nf) acc[mf][nf] = (f32x4){0.f, 0.f, 0.f, 0.f};

    int r = tid >> 1, h = tid & 1;
    int sw = r & 7;
    for (int k0 = 0; k0 < 2048; k0 += 64) {
        const u16* ap = (const u16*)A + (size_t)(gm0 + r) * 2048 + k0 + h * 32;
        const u16* bp = (const u16*)BT + (size_t)(n0 + r) * 2048 + k0 + h * 32;
#pragma unroll
        for (int q = 0; q < 4; ++q) {
            int blk = (h * 4 + q) ^ sw;
            *(uint4*)(As + r * 64 + blk * 8) = *(const uint4*)(ap + q * 8);
            *(uint4*)(Bs + r * 64 + blk * 8) = *(const uint4*)(bp + q * 8);
        }
        __syncthreads();
#pragma unroll
        for (int s = 0; s < 2; ++s) {
            f16x8 af[4], bfv[4];
#pragma unroll
            for (int mf = 0; mf < 4; ++mf) {
                int row = wr * 64 + mf * 16 + (lane & 15);
                int blk = (s * 4 + (lane >> 4)) ^ (row & 7);
                af[mf] = *(const f16x8*)(As + row * 64 + blk * 8);
            }
#pragma unroll
            for (int nf = 0; nf < 4; ++nf) {
                int row = wc * 64 + nf * 16 + (lane & 15);
                int blk = (s * 4 + (lane >> 4)) ^ (row & 7);
                bfv[nf] = *(const f16x8*)(Bs + row * 64 + blk * 8);
            }
#pragma unroll
            for (int mf = 0; mf < 4; ++mf)
#pragma unroll
                for (int nf = 0; nf < 4; ++nf)
                    acc[mf][nf] = __builtin_amdgcn_mfma_f32_16x16x32_f16(
                        af[mf], bfv[nf], acc[mf][nf], 0, 0, 0);
        }
        __syncthreads();
    }
    int j = gm0 >> 11;
    int ibase = (gm0 & (N_ - 1)) + wr * 64 + (lane >> 4) * 4;
#pragma unroll
    for (int nf = 0; nf < 4; ++nf) {
        int d = n0 + wc * 64 + nf * 16 + (lane & 15);
        float cs = 0.f;
#pragma unroll
        for (int mf = 0; mf < 4; ++mf) {
            float v0 = fabsf(acc[mf][nf][0]);
            float v1 = fabsf(acc[mf][nf][1]);
            float v2 = fabsf(acc[mf][nf][2]);
            float v3 = fabsf(acc[mf][nf][3]);
            cs += v0 + v1 + v2 + v3;
            ushort4 o;
            o.x = __half_as_ushort(__float2half(v0));
            o.y = __half_as_ushort(__float2half(v1));
            o.z = __half_as_ushort(__float2half(v2));
            o.w = __half_as_ushort(__float2half(v3));
            *(ushort4*)(U1T + (size_t)(j * 256 + d) * N_ + ibase + mf * 16) = o;
        }
        cs += __shfl_xor(cs, 16);
        cs += __shfl_xor(cs, 32);
        if ((lane >> 4) == 0) {
            int colg = n0 + wc * 64 + nf * 16 + lane;
            atomicAdd(&colsum[j * 256 + colg], cs);
        }
    }
}

// ---------------- MODE-1 MFMA GEMM (256x256, 512 threads): colsum2 of |Gh * U1T^T| -------
// XCD-chunked + T14 async-stage: next-tile global loads issue AFTER barrier #1 so the
// compiler's vmcnt-drain at barriers doesn't serialize them; latency hides under MFMA.
// K iteration order unchanged -> bitwise-identical results to the R12 kernel.
__global__ __launch_bounds__(512) void gemm256(const __half* __restrict__ A,
                                               const __half* __restrict__ BT,
                                               float* __restrict__ colsum) {
    __shared__ u16 As[256 * 64];
    __shared__ u16 Bs[256 * 64];
    int bid = blockIdx.x;
    int xcd = bid & 7, t2 = bid >> 3;      // t2 in 0..63
    int mt  = xcd * 8 + (t2 >> 3);         // m-tile 0..63
    int nt  = t2 & 7;                      // n-tile 0..7
    int tid = threadIdx.x;
    int w = tid >> 6, lane = tid & 63;
    int wr = w >> 2, wc = w & 3;           // 2 x 4 waves; per-wave tile 128m x 64n
    int gm0 = mt * 256, n0 = nt * 256;
    f32x4 acc[8][4];
#pragma unroll
    for (int mf = 0; mf < 8; ++mf)
#pragma unroll
        for (int nf = 0; nf < 4; ++nf) acc[mf][nf] = (f32x4){0.f, 0.f, 0.f, 0.f};

    int r = tid >> 1, h = tid & 1;         // 256 rows, 2 threads/row (32 u16 each)
    int sw = r & 7;
    const u16* apb = (const u16*)A + (size_t)(gm0 + r) * 2048 + h * 32;
    const u16* bpb = (const u16*)BT + (size_t)(n0 + r) * 2048 + h * 32;

    uint4 qa0[4], qb0[4], qa1[4], qb1[4];  // named double-buffered staging regs (rule #20)

    auto loadT = [&](int kk, uint4* QA, uint4* QB) {
        const u16* ap = apb + kk;
        const u16* bp = bpb + kk;
#pragma unroll
        for (int q = 0; q < 4; ++q) {
            QA[q] = *(const uint4*)(ap + q * 8);
            QB[q] = *(const uint4*)(bp + q * 8);
        }
    };
    auto stage = [&](const uint4* QA, const uint4* QB) {
#pragma unroll
        for (int q = 0; q < 4; ++q) {
            int blk = (h * 4 + q) ^ sw;    // XOR swizzle in 16B granules
            *(uint4*)(As + r * 64 + blk * 8) = QA[q];
            *(uint4*)(Bs + r * 64 + blk * 8) = QB[q];
        }
    };
    auto compute = [&]() {
#pragma unroll
        for (int s = 0; s < 2; ++s) {
            f16x8 af[8], bfv[4];
#pragma unroll
            for (int mf = 0; mf < 8; ++mf) {
                int row = wr * 128 + mf * 16 + (lane & 15);
                int blk = (s * 4 + (lane >> 4)) ^ (row & 7);
                af[mf] = *(const f16x8*)(As + row * 64 + blk * 8);
            }
#pragma unroll
            for (int nf = 0; nf < 4; ++nf) {
                int row = wc * 64 + nf * 16 + (lane & 15);
                int blk = (s * 4 + (lane >> 4)) ^ (row & 7);
                bfv[nf] = *(const f16x8*)(Bs + row * 64 + blk * 8);
            }
#pragma unroll
            for (int mf = 0; mf < 8; ++mf)
#pragma unroll
                for (int nf = 0; nf < 4; ++nf)
                    acc[mf][nf] = __builtin_amdgcn_mfma_f32_16x16x32_f16(
                        af[mf], bfv[nf], acc[mf][nf], 0, 0, 0);
        }
    };

    loadT(0, qa0, qb0);
    for (int k0 = 0; k0 < 2048; k0 += 128) {
        stage(qa0, qb0);
        __syncthreads();
        if (k0 + 64 < 2048) loadT(k0 + 64, qa1, qb1);   // prefetch hides under MFMA
        compute();
        __syncthreads();

        stage(qa1, qb1);
        __syncthreads();
        if (k0 + 128 < 2048) loadT(k0 + 128, qa0, qb0);
        compute();
        __syncthreads();
    }
    int j = gm0 >> 11;                     // 256-row m-tile never spans a j boundary
#pragma unroll
    for (int nf = 0; nf < 4; ++nf) {
        float cs = 0.f;
#pragma unroll
        for (int mf = 0; mf < 8; ++mf) {
            cs += fabsf(acc[mf][nf][0]) + fabsf(acc[mf][nf][1])
                + fabsf(acc[mf][nf][2]) + fabsf(acc[mf][nf][3]);
        }
        cs += __shfl_xor(cs, 16);
        cs += __shfl_xor(cs, 32);
        if ((lane >> 4) == 0) {
            int colg = n0 + wc * 64 + nf * 16 + lane;
            atomicAdd(&colsum[(((colg >> 8) * 8 + j) << 8) + (colg & 255)], cs);
        }
    }
}

__global__ __launch_bounds__(256) void fmean_kernel(const float* __restrict__ f, float* __restrict__ out) {
    int d = blockIdx.x, t = threadIdx.x;
    float s = 0.f;
    for (int n = t; n < N_; n += 256) s += f[(size_t)n * DF_ + d];
    __shared__ float red[256];
    red[t] = s; __syncthreads();
    for (int o = 128; o; o >>= 1) { if (t < o) red[t] += red[t + o]; __syncthreads(); }
    if (t == 0) out[d] = red[0] * (1.f / N_);
}

__global__ __launch_bounds__(256) void finalize_kernel(const float* __restrict__ sum1,
                                                       const float* __restrict__ sum2,
                                                       float* __restrict__ out) {
    int idx = blockIdx.x * 256 + threadIdx.x;
    if (idx < 2048)  out[256 + idx]  = sum1[idx] * (1.f / N_);
    if (idx < 16384) out[2304 + idx] = sum2[idx] * (1.f / N_);
}

// ---------------- host orchestration ----------------
extern "C" void kernel_launch(void* const* d_in, const int* in_sizes, int n_in,
                              void* d_out, int out_size, void* d_ws, size_t ws_size,
                              hipStream_t stream) {
    (void)in_sizes; (void)n_in;
    const float* W = (const float*)d_in[0];
    const float* f = (const float*)d_in[1];
    float* out = (float*)d_out;
    char* base = (char*)d_ws;
    size_t off = 0;
    auto take = [&](size_t bytes) -> char* {
        off = (off + 255) & ~(size_t)255;
        char* p = base + off; off += bytes; return p;
    };
    const size_t NSQ = (size_t)N_ * N_;
    float*  dh    = (float*)take((size_t)N_ * 4);
    float*  dr    = (float*)take((size_t)N_ * 4);
    int*    cnt   = (int*)take((size_t)N_ * 4);
    int*    perm  = (int*)take((size_t)N_ * 4);
    int*    cols  = (int*)take((size_t)N_ * ELLW_ * 4);
    float*  vals  = (float*)take((size_t)N_ * ELLW_ * 4);
    float*  coefs = (float*)take((size_t)J_ * M_ * 4);
    float*  sum1  = (float*)take(2048 * 4);
    float*  sum2  = (float*)take(16384 * 4);
    __half* Gh    = (__half*)take(NSQ * 2 * J_);                 //  67.1 MB
    __half* U1T   = (__half*)take((size_t)N_ * 2048 * 2);        //   8.4 MB
    __half* fhT   = (__half*)take((size_t)N_ * DF_ * 2);         //   1.0 MB
    off = (off + 255) & ~(size_t)255;
    const size_t slotBytes = NSQ * 2;
    long long rem = (long long)ws_size - (long long)off;
    int g = (int)(rem / (long long)slotBytes);
    if (g > GCAP_) g = GCAP_;
    if (g < 3) {                       // workspace too small — cannot run
        hipMemsetAsync(d_out, 0, (size_t)out_size * 4, stream);
        return;
    }
    __half* slots = (__half*)take((size_t)g * slotBytes);

    deg_kernel<<<N_, 256, 0, stream>>>(W, dh, dr);
    ell_kernel<<<N_, 64, 0, stream>>>(W, dh, cnt, cols, vals);
    perm_kernel<<<1, 256, 0, stream>>>(cnt, perm);
    coef_kernel<<<64, 256, 0, stream>>>(coefs);
    hipMemsetAsync(sum1, 0, 2048 * 4, stream);
    hipMemsetAsync(sum2, 0, 16384 * 4, stream);
    init_slots<<<N_, 256, 0, stream>>>(slots, slots + NSQ, cnt, cols, vals, dr);

    int k0 = 0;                        // start of current un-reduced group
    for (int k = 2; k < MUSE_; ++k) {
        cheb_fp16<<<2048, 256, 0, stream>>>(
            slots + (size_t)((k - 1) % g) * NSQ,
            slots + (size_t)((k - 2) % g) * NSQ,
            slots + (size_t)(k % g) * NSQ,
            cnt, cols, vals, dr, perm);
        if (k - k0 + 1 == g || k == MUSE_ - 1) {
            reduce_half<<<2048, 256, 0, stream>>>(slots, g, k0, k - k0 + 1,
                                                  k0 == 0 ? 1 : 0, coefs, Gh);
            k0 = k + 1;
        }
    }
    transpose_f16<<<DF_, 256, 0, stream>>>(f, fhT);
    mfma_gemm0<<<256, 256, 0, stream>>>(Gh, fhT, U1T, sum1);
    gemm256<<<512, 512, 0, stream>>>(Gh, U1T, sum2);
    fmean_kernel<<<DF_, 256, 0, stream>>>(f, out);
    finalize_kernel<<<64, 256, 0, stream>>>(sum1, sum2, out);
}

// Round 14
// 969.484 us; speedup vs baseline: 1.2572x; 1.2572x over previous
//
#include <hip/hip_runtime.h>
#include <hip/hip_fp16.h>
#include <math.h>

// ---------------- constants ----------------
constexpr int   N_   = 2048;
constexpr int   DF_  = 256;
constexpr int   J_   = 8;
constexpr int   ELLW_= 64;
constexpr int   M_   = 256;          // coefficient array stride (256-pt DCT quadrature)
constexpr int   MUSE_= 48;           // Chebyshev terms actually used (degree 47)
constexpr int   GCAP_= 12;           // ring 101MB; exactly 4 reduce passes (12x4)
constexpr float H_   = 1.01f;        // domain half-width  ([-0.01, 2.01])
constexpr float C0_  = 1.0f;         // domain center
constexpr float AF_  = 0.34657359027997264f;   // A = 3*ln(2)/6
constexpr float PI_F = 3.14159265358979323846f;

typedef _Float16 f16x8 __attribute__((ext_vector_type(8)));
typedef __attribute__((ext_vector_type(4))) float f32x4;
using u16 = unsigned short;

// ---------------- filter functions ----------------
__device__ __forceinline__ float g_hat_f(float x) {
    float val = 0.5f + 0.5f * cosf(2.f * PI_F * (x / AF_ + 0.5f));
    return (x <= 0.f && x > -AF_) ? val : 0.f;
}
__device__ __forceinline__ float wavelet_f(float lamb, int j) {
    float lmin = expf(AF_ * ((j - 1) / 3.0f - 1.0f));
    float lam  = fmaxf(lamb, lmin);
    return g_hat_f(logf(lam) - AF_ * (j - 1) / 3.0f);
}
__device__ __forceinline__ float filter_eval(float lamb, int jf) {
    if (jf == 0) {
        float g3 = 0.f;
        for (int j = 2; j <= 8; ++j) { float w = wavelet_f(lamb, j); g3 += w * w; }
        return sqrtf(fmaxf(1.5f - g3, 0.f));
    }
    return wavelet_f(lamb, jf + 1);
}

// ---------------- setup kernels ----------------
__global__ __launch_bounds__(256) void deg_kernel(const float* __restrict__ W,
                                                  float* __restrict__ dh,
                                                  float* __restrict__ dr) {
    int i = blockIdx.x, t = threadIdx.x;
    const float4* row = (const float4*)(W + (size_t)i * N_);
    float s = 0.f;
    for (int c = t; c < N_ / 4; c += 256) { float4 v = row[c]; s += v.x + v.y + v.z + v.w; }
    __shared__ float red[256];
    red[t] = s; __syncthreads();
    for (int o = 128; o; o >>= 1) { if (t < o) red[t] += red[t + o]; __syncthreads(); }
    if (t == 0) {
        float deg = red[0];
        float dhi = 1.f / sqrtf(fmaxf(deg, 1.f));
        dh[i] = dhi;
        dr[i] = (dhi * dhi * deg - C0_) / H_;
    }
}

// ELL build: all 64 entries pre-filled with (col=i, val=0) pads; cnt rounded up to mult of 8.
__global__ __launch_bounds__(64) void ell_kernel(const float* __restrict__ W,
                                                 const float* __restrict__ dh,
                                                 int* __restrict__ cnt,
                                                 int* __restrict__ cols,
                                                 float* __restrict__ vals) {
    int i = blockIdx.x, lane = threadIdx.x;
    cols[i * ELLW_ + lane] = i;            // pad defaults
    vals[i * ELLW_ + lane] = 0.f;
    __syncthreads();
    const float* row = W + (size_t)i * N_;
    unsigned long long lt = (1ull << lane) - 1ull;
    int base = 0;
    float dhi = dh[i];
    for (int c = 0; c < N_; c += 64) {
        float v = row[c + lane];
        unsigned long long m = __ballot(v != 0.f);
        if (v != 0.f) {
            int pos = base + __popcll(m & lt);
            if (pos < ELLW_) {
                cols[i * ELLW_ + pos] = c + lane;
                vals[i * ELLW_ + pos] = dhi * dh[c + lane] / H_;
            }
        }
        base += __popcll(m);
    }
    if (lane == 0) {
        int n = base < ELLW_ ? base : ELLW_;
        cnt[i] = (n + 7) & ~7;             // padded count (pads are no-ops)
    }
}

// deterministic counting sort of rows by padded degree -> perm (parallel scan version)
__global__ __launch_bounds__(256) void perm_kernel(const int* __restrict__ cnt,
                                                   int* __restrict__ perm) {
    __shared__ int hist[9][256];           // per-thread bucket counts -> exclusive offsets
    __shared__ int bstart[9];
    int t = threadIdx.x;
    int b[8];
    int h[9] = {0, 0, 0, 0, 0, 0, 0, 0, 0};
#pragma unroll
    for (int u = 0; u < 8; ++u) {
        b[u] = cnt[t * 8 + u] >> 3;        // bucket 0..8
        h[b[u]]++;
    }
#pragma unroll
    for (int bb = 0; bb < 9; ++bb) hist[bb][t] = h[bb];
    __syncthreads();
    if (t < 9) {                           // exclusive scan across threads, per bucket
        int acc = 0;
        for (int k = 0; k < 256; ++k) { int v = hist[t][k]; hist[t][k] = acc; acc += v; }
        bstart[t] = acc;                   // bucket total
    }
    __syncthreads();
    if (t == 0) {                          // exclusive scan of bucket totals
        int acc = 0;
        for (int bb = 0; bb < 9; ++bb) { int v = bstart[bb]; bstart[bb] = acc; acc += v; }
    }
    __syncthreads();
    int run[9] = {0, 0, 0, 0, 0, 0, 0, 0, 0};
#pragma unroll
    for (int u = 0; u < 8; ++u) {
        int bb = b[u];
        perm[bstart[bb] + hist[bb][t] + run[bb]] = t * 8 + u;
        run[bb]++;
    }
}

// parallel DCT: 64 blocks = 8 filters x 8 output-chunks; 8 threads per output.
__global__ __launch_bounds__(256) void coef_kernel(float* __restrict__ coefs) {
    __shared__ float fv[M_];
    int j     = blockIdx.x >> 3;
    int chunk = blockIdx.x & 7;
    int t = threadIdx.x;
    float theta = PI_F * (t + 0.5f) / M_;
    fv[t] = filter_eval(C0_ + H_ * cosf(theta), j);
    __syncthreads();
    int out = chunk * 32 + (t >> 3);       // output index 0..255
    int seg = t & 7;                       // 8 threads per output
    float s = 0.f;
    for (int i = seg * 32; i < seg * 32 + 32; ++i)
        s += fv[i] * cosf(PI_F * out * (i + 0.5f) / M_);
    s += __shfl_xor(s, 1);
    s += __shfl_xor(s, 2);
    s += __shfl_xor(s, 4);
    if (seg == 0) coefs[j * M_ + out] = s * ((out == 0 ? 1.f : 2.f) / M_);
}

// slot0 = I (fp16), slot1 = scaled L-tilde (fp16)
__global__ __launch_bounds__(256) void init_slots(__half* __restrict__ S0, __half* __restrict__ S1,
                                                  const int* __restrict__ cnt, const int* __restrict__ cols,
                                                  const float* __restrict__ vals, const float* __restrict__ dr) {
    int i = blockIdx.x, t = threadIdx.x;
    size_t ro = (size_t)i * N_;
    for (int c = t * 8; c < N_; c += 2048) {
        *(uint4*)(S0 + ro + c) = uint4{0, 0, 0, 0};
        *(uint4*)(S1 + ro + c) = uint4{0, 0, 0, 0};
    }
    __syncthreads();
    int n = cnt[i];
    if (t < n) {
        int c = cols[i * ELLW_ + t];
        float v = -vals[i * ELLW_ + t];
        if (v != 0.f) S1[ro + c] = __float2half(v);   // skip pads (col=i, val=0)
    }
    __syncthreads();
    if (t == 0) {
        S0[ro + i] = __float2half(1.f);
        S1[ro + i] = __float2half(dr[i]);
    }
}

// ------- Chebyshev step, XCD-striped + degree-sorted rows (proven R8 form: unroll-8) -----
__global__ __launch_bounds__(256) void cheb_fp16(const __half* __restrict__ X,
                                                 const __half* __restrict__ Tprev,
                                                 __half* __restrict__ Tnext,
                                                 const int* __restrict__ cnt,
                                                 const int* __restrict__ cols,
                                                 const float* __restrict__ vals,
                                                 const float* __restrict__ dr,
                                                 const int* __restrict__ perm) {
    int strp = blockIdx.x & 7;
    int rg   = blockIdx.x >> 3;
    int tr   = threadIdx.x >> 5;           // 0..7: row within block
    int lr   = threadIdx.x & 31;
    __shared__ int   sperm[8];
    __shared__ int   scnt[8];
    __shared__ int   scols[8][ELLW_];
    __shared__ float svals[8][ELLW_];
    if (threadIdx.x < 8) {
        int p = perm[rg * 8 + threadIdx.x];
        sperm[threadIdx.x] = p;
        scnt[threadIdx.x]  = cnt[p];
    }
    __syncthreads();
    {
        int e = threadIdx.x & 63, r0 = threadIdx.x >> 6;      // r0 in 0..3
        int p0 = sperm[r0], p1 = sperm[r0 + 4];
        scols[r0][e] = cols[p0 * ELLW_ + e];     svals[r0][e] = vals[p0 * ELLW_ + e];
        scols[r0 + 4][e] = cols[p1 * ELLW_ + e]; svals[r0 + 4][e] = vals[p1 * ELLW_ + e];
    }
    __syncthreads();
    int i   = sperm[tr];
    int n   = scnt[tr];                      // multiple of 8 (or 0)
    int col = strp * 256 + lr * 8;
    float a[8] = {0, 0, 0, 0, 0, 0, 0, 0};
    for (int e0 = 0; e0 < n; e0 += 8) {
        uint4 q[8];
        float v[8];
#pragma unroll
        for (int u = 0; u < 8; ++u) {
            int c = scols[tr][e0 + u];
            v[u] = svals[tr][e0 + u];
            q[u] = *(const uint4*)(X + (size_t)c * N_ + col);
        }
#pragma unroll
        for (int u = 0; u < 8; ++u) {
            const __half2* h = (const __half2*)&q[u];
            float2 f0 = __half22float2(h[0]), f1 = __half22float2(h[1]);
            float2 f2 = __half22float2(h[2]), f3 = __half22float2(h[3]);
            a[0] -= v[u] * f0.x; a[1] -= v[u] * f0.y;
            a[2] -= v[u] * f1.x; a[3] -= v[u] * f1.y;
            a[4] -= v[u] * f2.x; a[5] -= v[u] * f2.y;
            a[6] -= v[u] * f3.x; a[7] -= v[u] * f3.y;
        }
    }
    size_t po = (size_t)i * N_ + col;
    {   // diagonal term
        float d = dr[i];
        uint4 q = *(const uint4*)(X + po);
        const __half2* h = (const __half2*)&q;
        float2 f0 = __half22float2(h[0]), f1 = __half22float2(h[1]);
        float2 f2 = __half22float2(h[2]), f3 = __half22float2(h[3]);
        a[0] += d * f0.x; a[1] += d * f0.y; a[2] += d * f1.x; a[3] += d * f1.y;
        a[4] += d * f2.x; a[5] += d * f2.y; a[6] += d * f3.x; a[7] += d * f3.y;
    }
    uint4 qp = *(const uint4*)(Tprev + po);
    const __half2* hp = (const __half2*)&qp;
    float2 p0 = __half22float2(hp[0]), p1 = __half22float2(hp[1]);
    float2 p2 = __half22float2(hp[2]), p3 = __half22float2(hp[3]);
    __half2 s0 = __floats2half2_rn(2.f * a[0] - p0.x, 2.f * a[1] - p0.y);
    __half2 s1 = __floats2half2_rn(2.f * a[2] - p1.x, 2.f * a[3] - p1.y);
    __half2 s2 = __floats2half2_rn(2.f * a[4] - p2.x, 2.f * a[5] - p2.y);
    __half2 s3 = __floats2half2_rn(2.f * a[6] - p3.x, 2.f * a[7] - p3.y);
    uint4 sq;
    sq.x = *(const unsigned int*)&s0; sq.y = *(const unsigned int*)&s1;
    sq.z = *(const unsigned int*)&s2; sq.w = *(const unsigned int*)&s3;
    *(uint4*)(Tnext + po) = sq;
}

// ---------------- group reduction: Gh_j += sum_{k in [k0,k0+nslot)} b_{jk} * slot(k%g) -------
__global__ __launch_bounds__(256) void reduce_half(const __half* __restrict__ slots,
                                                   int g, int k0, int nslot, int initG,
                                                   const float* __restrict__ coefs,
                                                   __half* __restrict__ Gh) {
    const size_t NSQ = (size_t)N_ * N_;
    size_t idx = ((size_t)blockIdx.x * 256 + threadIdx.x) * 8;
    __shared__ float sc[J_ * 64];
    for (int x = threadIdx.x; x < J_ * nslot; x += 256) {
        int j = x / nslot, s = x - j * nslot;
        sc[j * 64 + s] = coefs[j * M_ + k0 + s];
    }
    __syncthreads();
    float acc[J_][8];
#pragma unroll
    for (int j = 0; j < J_; ++j) {
        if (initG) {
#pragma unroll
            for (int r = 0; r < 8; ++r) acc[j][r] = 0.f;
        } else {
            uint4 q = *(const uint4*)(Gh + (size_t)j * NSQ + idx);
            const __half2* h = (const __half2*)&q;
            float2 f0 = __half22float2(h[0]), f1 = __half22float2(h[1]);
            float2 f2 = __half22float2(h[2]), f3 = __half22float2(h[3]);
            acc[j][0] = f0.x; acc[j][1] = f0.y; acc[j][2] = f1.x; acc[j][3] = f1.y;
            acc[j][4] = f2.x; acc[j][5] = f2.y; acc[j][6] = f3.x; acc[j][7] = f3.y;
        }
    }
    for (int s = 0; s < nslot; ++s) {
        int slot = (k0 + s) % g;
        uint4 q = *(const uint4*)(slots + (size_t)slot * NSQ + idx);
        const __half2* h = (const __half2*)&q;
        float2 f0 = __half22float2(h[0]), f1 = __half22float2(h[1]);
        float2 f2 = __half22float2(h[2]), f3 = __half22float2(h[3]);
        float f[8] = {f0.x, f0.y, f1.x, f1.y, f2.x, f2.y, f3.x, f3.y};
#pragma unroll
        for (int j = 0; j < J_; ++j) {
            float c = sc[j * 64 + s];
#pragma unroll
            for (int r = 0; r < 8; ++r) acc[j][r] += c * f[r];
        }
    }
#pragma unroll
    for (int j = 0; j < J_; ++j) {
        __half2 o0 = __floats2half2_rn(acc[j][0], acc[j][1]);
        __half2 o1 = __floats2half2_rn(acc[j][2], acc[j][3]);
        __half2 o2 = __floats2half2_rn(acc[j][4], acc[j][5]);
        __half2 o3 = __floats2half2_rn(acc[j][6], acc[j][7]);
        uint4 o;
        o.x = *(const unsigned int*)&o0; o.y = *(const unsigned int*)&o1;
        o.z = *(const unsigned int*)&o2; o.w = *(const unsigned int*)&o3;
        *(uint4*)(Gh + (size_t)j * NSQ + idx) = o;
    }
}

// ---------------- f [2048][256] f32  ->  fhT [256][2048] f16 (transposed) ----------------
__global__ __launch_bounds__(256) void transpose_f16(const float* __restrict__ src,
                                                     __half* __restrict__ dst) {
    int d = blockIdx.x;                    // 256 output rows
    int i0 = threadIdx.x * 8;              // 8 nodes per thread
    __half h[8];
#pragma unroll
    for (int u = 0; u < 8; ++u) h[u] = __float2half(src[(size_t)(i0 + u) * DF_ + d]);
    uint4 o;
    __half2* hp = (__half2*)&o;
    hp[0] = __half2{h[0], h[1]}; hp[1] = __half2{h[2], h[3]};
    hp[2] = __half2{h[4], h[5]}; hp[3] = __half2{h[6], h[7]};
    *(uint4*)(dst + (size_t)d * N_ + i0) = o;
}

// ---------------- MODE-0 MFMA GEMM (128x128): U1T = |Gh * fhT^T|, colsum1 ----------------
// 1D grid 256, XCD-chunked: xcd = bid&7 owns m-chunk [xcd*16, xcd*16+16) x 2 n-tiles.
__global__ __launch_bounds__(256) void mfma_gemm0(const __half* __restrict__ A,
                                                  const __half* __restrict__ BT,
                                                  __half* __restrict__ U1T,
                                                  float* __restrict__ colsum) {
    __shared__ u16 As[128 * 64];
    __shared__ u16 Bs[128 * 64];
    int bid = blockIdx.x;
    int xcd = bid & 7, t2 = bid >> 3;      // t2 in 0..31
    int mt  = xcd * 16 + (t2 >> 1);        // m-tile 0..127
    int nt  = t2 & 1;                      // n-tile 0..1
    int tid = threadIdx.x;
    int w = tid >> 6, lane = tid & 63;
    int wr = w >> 1, wc = w & 1;
    int gm0 = mt * 128, n0 = nt * 128;
    f32x4 acc[4][4];
#pragma unroll
    for (int mf = 0; mf < 4; ++mf)
#pragma unroll
        for (int nf = 0; nf < 4; ++nf) acc[mf][nf] = (f32x4){0.f, 0.f, 0.f, 0.f};

    int r = tid >> 1, h = tid & 1;
    int sw = r & 7;
    for (int k0 = 0; k0 < 2048; k0 += 64) {
        const u16* ap = (const u16*)A + (size_t)(gm0 + r) * 2048 + k0 + h * 32;
        const u16* bp = (const u16*)BT + (size_t)(n0 + r) * 2048 + k0 + h * 32;
#pragma unroll
        for (int q = 0; q < 4; ++q) {
            int blk = (h * 4 + q) ^ sw;
            *(uint4*)(As + r * 64 + blk * 8) = *(const uint4*)(ap + q * 8);
            *(uint4*)(Bs + r * 64 + blk * 8) = *(const uint4*)(bp + q * 8);
        }
        __syncthreads();
#pragma unroll
        for (int s = 0; s < 2; ++s) {
            f16x8 af[4], bfv[4];
#pragma unroll
            for (int mf = 0; mf < 4; ++mf) {
                int row = wr * 64 + mf * 16 + (lane & 15);
                int blk = (s * 4 + (lane >> 4)) ^ (row & 7);
                af[mf] = *(const f16x8*)(As + row * 64 + blk * 8);
            }
#pragma unroll
            for (int nf = 0; nf < 4; ++nf) {
                int row = wc * 64 + nf * 16 + (lane & 15);
                int blk = (s * 4 + (lane >> 4)) ^ (row & 7);
                bfv[nf] = *(const f16x8*)(Bs + row * 64 + blk * 8);
            }
#pragma unroll
            for (int mf = 0; mf < 4; ++mf)
#pragma unroll
                for (int nf = 0; nf < 4; ++nf)
                    acc[mf][nf] = __builtin_amdgcn_mfma_f32_16x16x32_f16(
                        af[mf], bfv[nf], acc[mf][nf], 0, 0, 0);
        }
        __syncthreads();
    }
    int j = gm0 >> 11;
    int ibase = (gm0 & (N_ - 1)) + wr * 64 + (lane >> 4) * 4;
#pragma unroll
    for (int nf = 0; nf < 4; ++nf) {
        int d = n0 + wc * 64 + nf * 16 + (lane & 15);
        float cs = 0.f;
#pragma unroll
        for (int mf = 0; mf < 4; ++mf) {
            float v0 = fabsf(acc[mf][nf][0]);
            float v1 = fabsf(acc[mf][nf][1]);
            float v2 = fabsf(acc[mf][nf][2]);
            float v3 = fabsf(acc[mf][nf][3]);
            cs += v0 + v1 + v2 + v3;
            ushort4 o;
            o.x = __half_as_ushort(__float2half(v0));
            o.y = __half_as_ushort(__float2half(v1));
            o.z = __half_as_ushort(__float2half(v2));
            o.w = __half_as_ushort(__float2half(v3));
            *(ushort4*)(U1T + (size_t)(j * 256 + d) * N_ + ibase + mf * 16) = o;
        }
        cs += __shfl_xor(cs, 16);
        cs += __shfl_xor(cs, 32);
        if ((lane >> 4) == 0) {
            int colg = n0 + wc * 64 + nf * 16 + lane;
            atomicAdd(&colsum[j * 256 + colg], cs);
        }
    }
}

// ---------------- MODE-1 MFMA GEMM (256x256, 512 threads): colsum2 of |Gh * U1T^T| -------
// R12 proven form (no reg double-buffer — R13's lambda-pointer staging spilled to scratch).
// 1D grid 512, XCD-chunked: xcd = bid&7 owns m-chunk [xcd*8, xcd*8+8) x all 8 n-tiles.
__global__ __launch_bounds__(512) void gemm256(const __half* __restrict__ A,
                                               const __half* __restrict__ BT,
                                               float* __restrict__ colsum) {
    __shared__ u16 As[256 * 64];
    __shared__ u16 Bs[256 * 64];
    int bid = blockIdx.x;
    int xcd = bid & 7, t2 = bid >> 3;      // t2 in 0..63
    int mt  = xcd * 8 + (t2 >> 3);         // m-tile 0..63
    int nt  = t2 & 7;                      // n-tile 0..7
    int tid = threadIdx.x;
    int w = tid >> 6, lane = tid & 63;
    int wr = w >> 2, wc = w & 3;           // 2 x 4 waves; per-wave tile 128m x 64n
    int gm0 = mt * 256, n0 = nt * 256;
    f32x4 acc[8][4];
#pragma unroll
    for (int mf = 0; mf < 8; ++mf)
#pragma unroll
        for (int nf = 0; nf < 4; ++nf) acc[mf][nf] = (f32x4){0.f, 0.f, 0.f, 0.f};

    int r = tid >> 1, h = tid & 1;         // 256 rows, 2 threads/row (32 u16 each)
    int sw = r & 7;
    for (int k0 = 0; k0 < 2048; k0 += 64) {
        const u16* ap = (const u16*)A + (size_t)(gm0 + r) * 2048 + k0 + h * 32;
        const u16* bp = (const u16*)BT + (size_t)(n0 + r) * 2048 + k0 + h * 32;
#pragma unroll
        for (int q = 0; q < 4; ++q) {
            int blk = (h * 4 + q) ^ sw;    // XOR swizzle in 16B granules
            *(uint4*)(As + r * 64 + blk * 8) = *(const uint4*)(ap + q * 8);
            *(uint4*)(Bs + r * 64 + blk * 8) = *(const uint4*)(bp + q * 8);
        }
        __syncthreads();
#pragma unroll
        for (int s = 0; s < 2; ++s) {
            f16x8 af[8], bfv[4];
#pragma unroll
            for (int mf = 0; mf < 8; ++mf) {
                int row = wr * 128 + mf * 16 + (lane & 15);
                int blk = (s * 4 + (lane >> 4)) ^ (row & 7);
                af[mf] = *(const f16x8*)(As + row * 64 + blk * 8);
            }
#pragma unroll
            for (int nf = 0; nf < 4; ++nf) {
                int row = wc * 64 + nf * 16 + (lane & 15);
                int blk = (s * 4 + (lane >> 4)) ^ (row & 7);
                bfv[nf] = *(const f16x8*)(Bs + row * 64 + blk * 8);
            }
#pragma unroll
            for (int mf = 0; mf < 8; ++mf)
#pragma unroll
                for (int nf = 0; nf < 4; ++nf)
                    acc[mf][nf] = __builtin_amdgcn_mfma_f32_16x16x32_f16(
                        af[mf], bfv[nf], acc[mf][nf], 0, 0, 0);
        }
        __syncthreads();
    }
    int j = gm0 >> 11;                     // 256-row m-tile never spans a j boundary
#pragma unroll
    for (int nf = 0; nf < 4; ++nf) {
        float cs = 0.f;
#pragma unroll
        for (int mf = 0; mf < 8; ++mf) {
            cs += fabsf(acc[mf][nf][0]) + fabsf(acc[mf][nf][1])
                + fabsf(acc[mf][nf][2]) + fabsf(acc[mf][nf][3]);
        }
        cs += __shfl_xor(cs, 16);
        cs += __shfl_xor(cs, 32);
        if ((lane >> 4) == 0) {
            int colg = n0 + wc * 64 + nf * 16 + lane;
            atomicAdd(&colsum[(((colg >> 8) * 8 + j) << 8) + (colg & 255)], cs);
        }
    }
}

__global__ __launch_bounds__(256) void fmean_kernel(const float* __restrict__ f, float* __restrict__ out) {
    int d = blockIdx.x, t = threadIdx.x;
    float s = 0.f;
    for (int n = t; n < N_; n += 256) s += f[(size_t)n * DF_ + d];
    __shared__ float red[256];
    red[t] = s; __syncthreads();
    for (int o = 128; o; o >>= 1) { if (t < o) red[t] += red[t + o]; __syncthreads(); }
    if (t == 0) out[d] = red[0] * (1.f / N_);
}

__global__ __launch_bounds__(256) void finalize_kernel(const float* __restrict__ sum1,
                                                       const float* __restrict__ sum2,
                                                       float* __restrict__ out) {
    int idx = blockIdx.x * 256 + threadIdx.x;
    if (idx < 2048)  out[256 + idx]  = sum1[idx] * (1.f / N_);
    if (idx < 16384) out[2304 + idx] = sum2[idx] * (1.f / N_);
}

// ---------------- host orchestration ----------------
extern "C" void kernel_launch(void* const* d_in, const int* in_sizes, int n_in,
                              void* d_out, int out_size, void* d_ws, size_t ws_size,
                              hipStream_t stream) {
    (void)in_sizes; (void)n_in;
    const float* W = (const float*)d_in[0];
    const float* f = (const float*)d_in[1];
    float* out = (float*)d_out;
    char* base = (char*)d_ws;
    size_t off = 0;
    auto take = [&](size_t bytes) -> char* {
        off = (off + 255) & ~(size_t)255;
        char* p = base + off; off += bytes; return p;
    };
    const size_t NSQ = (size_t)N_ * N_;
    float*  dh    = (float*)take((size_t)N_ * 4);
    float*  dr    = (float*)take((size_t)N_ * 4);
    int*    cnt   = (int*)take((size_t)N_ * 4);
    int*    perm  = (int*)take((size_t)N_ * 4);
    int*    cols  = (int*)take((size_t)N_ * ELLW_ * 4);
    float*  vals  = (float*)take((size_t)N_ * ELLW_ * 4);
    float*  coefs = (float*)take((size_t)J_ * M_ * 4);
    float*  sum1  = (float*)take(2048 * 4);
    float*  sum2  = (float*)take(16384 * 4);
    __half* Gh    = (__half*)take(NSQ * 2 * J_);                 //  67.1 MB
    __half* U1T   = (__half*)take((size_t)N_ * 2048 * 2);        //   8.4 MB
    __half* fhT   = (__half*)take((size_t)N_ * DF_ * 2);         //   1.0 MB
    off = (off + 255) & ~(size_t)255;
    const size_t slotBytes = NSQ * 2;
    long long rem = (long long)ws_size - (long long)off;
    int g = (int)(rem / (long long)slotBytes);
    if (g > GCAP_) g = GCAP_;
    if (g < 3) {                       // workspace too small — cannot run
        hipMemsetAsync(d_out, 0, (size_t)out_size * 4, stream);
        return;
    }
    __half* slots = (__half*)take((size_t)g * slotBytes);

    deg_kernel<<<N_, 256, 0, stream>>>(W, dh, dr);
    ell_kernel<<<N_, 64, 0, stream>>>(W, dh, cnt, cols, vals);
    perm_kernel<<<1, 256, 0, stream>>>(cnt, perm);
    coef_kernel<<<64, 256, 0, stream>>>(coefs);
    hipMemsetAsync(sum1, 0, 2048 * 4, stream);
    hipMemsetAsync(sum2, 0, 16384 * 4, stream);
    init_slots<<<N_, 256, 0, stream>>>(slots, slots + NSQ, cnt, cols, vals, dr);

    int k0 = 0;                        // start of current un-reduced group
    for (int k = 2; k < MUSE_; ++k) {
        cheb_fp16<<<2048, 256, 0, stream>>>(
            slots + (size_t)((k - 1) % g) * NSQ,
            slots + (size_t)((k - 2) % g) * NSQ,
            slots + (size_t)(k % g) * NSQ,
            cnt, cols, vals, dr, perm);
        if (k - k0 + 1 == g || k == MUSE_ - 1) {
            reduce_half<<<2048, 256, 0, stream>>>(slots, g, k0, k - k0 + 1,
                                                  k0 == 0 ? 1 : 0, coefs, Gh);
            k0 = k + 1;
        }
    }
    transpose_f16<<<DF_, 256, 0, stream>>>(f, fhT);
    mfma_gemm0<<<256, 256, 0, stream>>>(Gh, fhT, U1T, sum1);
    gemm256<<<512, 512, 0, stream>>>(Gh, U1T, sum2);
    fmean_kernel<<<DF_, 256, 0, stream>>>(f, out);
    finalize_kernel<<<64, 256, 0, stream>>>(sum1, sum2, out);
}

// Round 15
// 838.240 us; speedup vs baseline: 1.4540x; 1.1566x over previous
//
#include <hip/hip_runtime.h>
#include <hip/hip_fp16.h>
#include <math.h>

// ---------------- constants ----------------
constexpr int   N_   = 2048;
constexpr int   DF_  = 256;
constexpr int   J_   = 8;
constexpr int   ELLW_= 64;
constexpr int   M_   = 256;          // coefficient array stride (256-pt DCT quadrature)
constexpr int   MUSE_= 40;           // Chebyshev terms actually used (degree 39)
constexpr int   GCAP_= 10;           // ring 84MB; exactly 4 reduce passes (10x4)
constexpr float H_   = 1.01f;        // domain half-width  ([-0.01, 2.01])
constexpr float C0_  = 1.0f;         // domain center
constexpr float AF_  = 0.34657359027997264f;   // A = 3*ln(2)/6
constexpr float PI_F = 3.14159265358979323846f;

typedef _Float16 f16x8 __attribute__((ext_vector_type(8)));
typedef __attribute__((ext_vector_type(4))) float f32x4;
using u16 = unsigned short;
typedef __attribute__((address_space(3))) unsigned int lds_u32;
typedef const __attribute__((address_space(1))) unsigned int glb_u32;

// ---------------- filter functions ----------------
__device__ __forceinline__ float g_hat_f(float x) {
    float val = 0.5f + 0.5f * cosf(2.f * PI_F * (x / AF_ + 0.5f));
    return (x <= 0.f && x > -AF_) ? val : 0.f;
}
__device__ __forceinline__ float wavelet_f(float lamb, int j) {
    float lmin = expf(AF_ * ((j - 1) / 3.0f - 1.0f));
    float lam  = fmaxf(lamb, lmin);
    return g_hat_f(logf(lam) - AF_ * (j - 1) / 3.0f);
}
__device__ __forceinline__ float filter_eval(float lamb, int jf) {
    if (jf == 0) {
        float g3 = 0.f;
        for (int j = 2; j <= 8; ++j) { float w = wavelet_f(lamb, j); g3 += w * w; }
        return sqrtf(fmaxf(1.5f - g3, 0.f));
    }
    return wavelet_f(lamb, jf + 1);
}

// ---------------- setup kernels ----------------
__global__ __launch_bounds__(256) void deg_kernel(const float* __restrict__ W,
                                                  float* __restrict__ dh,
                                                  float* __restrict__ dr) {
    int i = blockIdx.x, t = threadIdx.x;
    const float4* row = (const float4*)(W + (size_t)i * N_);
    float s = 0.f;
    for (int c = t; c < N_ / 4; c += 256) { float4 v = row[c]; s += v.x + v.y + v.z + v.w; }
    __shared__ float red[256];
    red[t] = s; __syncthreads();
    for (int o = 128; o; o >>= 1) { if (t < o) red[t] += red[t + o]; __syncthreads(); }
    if (t == 0) {
        float deg = red[0];
        float dhi = 1.f / sqrtf(fmaxf(deg, 1.f));
        dh[i] = dhi;
        dr[i] = (dhi * dhi * deg - C0_) / H_;
    }
}

// ELL build: all 64 entries pre-filled with (col=i, val=0) pads; cnt rounded up to mult of 8.
__global__ __launch_bounds__(64) void ell_kernel(const float* __restrict__ W,
                                                 const float* __restrict__ dh,
                                                 int* __restrict__ cnt,
                                                 int* __restrict__ cols,
                                                 float* __restrict__ vals) {
    int i = blockIdx.x, lane = threadIdx.x;
    cols[i * ELLW_ + lane] = i;            // pad defaults
    vals[i * ELLW_ + lane] = 0.f;
    __syncthreads();
    const float* row = W + (size_t)i * N_;
    unsigned long long lt = (1ull << lane) - 1ull;
    int base = 0;
    float dhi = dh[i];
    for (int c = 0; c < N_; c += 64) {
        float v = row[c + lane];
        unsigned long long m = __ballot(v != 0.f);
        if (v != 0.f) {
            int pos = base + __popcll(m & lt);
            if (pos < ELLW_) {
                cols[i * ELLW_ + pos] = c + lane;
                vals[i * ELLW_ + pos] = dhi * dh[c + lane] / H_;
            }
        }
        base += __popcll(m);
    }
    if (lane == 0) {
        int n = base < ELLW_ ? base : ELLW_;
        cnt[i] = (n + 7) & ~7;             // padded count (pads are no-ops)
    }
}

// deterministic counting sort of rows by padded degree -> perm (parallel scan version)
__global__ __launch_bounds__(256) void perm_kernel(const int* __restrict__ cnt,
                                                   int* __restrict__ perm) {
    __shared__ int hist[9][256];           // per-thread bucket counts -> exclusive offsets
    __shared__ int bstart[9];
    int t = threadIdx.x;
    int b[8];
    int h[9] = {0, 0, 0, 0, 0, 0, 0, 0, 0};
#pragma unroll
    for (int u = 0; u < 8; ++u) {
        b[u] = cnt[t * 8 + u] >> 3;        // bucket 0..8
        h[b[u]]++;
    }
#pragma unroll
    for (int bb = 0; bb < 9; ++bb) hist[bb][t] = h[bb];
    __syncthreads();
    if (t < 9) {                           // exclusive scan across threads, per bucket
        int acc = 0;
        for (int k = 0; k < 256; ++k) { int v = hist[t][k]; hist[t][k] = acc; acc += v; }
        bstart[t] = acc;                   // bucket total
    }
    __syncthreads();
    if (t == 0) {                          // exclusive scan of bucket totals
        int acc = 0;
        for (int bb = 0; bb < 9; ++bb) { int v = bstart[bb]; bstart[bb] = acc; acc += v; }
    }
    __syncthreads();
    int run[9] = {0, 0, 0, 0, 0, 0, 0, 0, 0};
#pragma unroll
    for (int u = 0; u < 8; ++u) {
        int bb = b[u];
        perm[bstart[bb] + hist[bb][t] + run[bb]] = t * 8 + u;
        run[bb]++;
    }
}

// parallel DCT: 64 blocks = 8 filters x 8 output-chunks; 8 threads per output.
__global__ __launch_bounds__(256) void coef_kernel(float* __restrict__ coefs) {
    __shared__ float fv[M_];
    int j     = blockIdx.x >> 3;
    int chunk = blockIdx.x & 7;
    int t = threadIdx.x;
    float theta = PI_F * (t + 0.5f) / M_;
    fv[t] = filter_eval(C0_ + H_ * cosf(theta), j);
    __syncthreads();
    int out = chunk * 32 + (t >> 3);       // output index 0..255
    int seg = t & 7;                       // 8 threads per output
    float s = 0.f;
    for (int i = seg * 32; i < seg * 32 + 32; ++i)
        s += fv[i] * cosf(PI_F * out * (i + 0.5f) / M_);
    s += __shfl_xor(s, 1);
    s += __shfl_xor(s, 2);
    s += __shfl_xor(s, 4);
    if (seg == 0) coefs[j * M_ + out] = s * ((out == 0 ? 1.f : 2.f) / M_);
}

// slot0 = I (fp16), slot1 = scaled L-tilde (fp16)
__global__ __launch_bounds__(256) void init_slots(__half* __restrict__ S0, __half* __restrict__ S1,
                                                  const int* __restrict__ cnt, const int* __restrict__ cols,
                                                  const float* __restrict__ vals, const float* __restrict__ dr) {
    int i = blockIdx.x, t = threadIdx.x;
    size_t ro = (size_t)i * N_;
    for (int c = t * 8; c < N_; c += 2048) {
        *(uint4*)(S0 + ro + c) = uint4{0, 0, 0, 0};
        *(uint4*)(S1 + ro + c) = uint4{0, 0, 0, 0};
    }
    __syncthreads();
    int n = cnt[i];
    if (t < n) {
        int c = cols[i * ELLW_ + t];
        float v = -vals[i * ELLW_ + t];
        if (v != 0.f) S1[ro + c] = __float2half(v);   // skip pads (col=i, val=0)
    }
    __syncthreads();
    if (t == 0) {
        S0[ro + i] = __float2half(1.f);
        S1[ro + i] = __float2half(dr[i]);
    }
}

// ------- Chebyshev step, XCD-striped + degree-sorted rows (proven R8 form: unroll-8) -----
__global__ __launch_bounds__(256) void cheb_fp16(const __half* __restrict__ X,
                                                 const __half* __restrict__ Tprev,
                                                 __half* __restrict__ Tnext,
                                                 const int* __restrict__ cnt,
                                                 const int* __restrict__ cols,
                                                 const float* __restrict__ vals,
                                                 const float* __restrict__ dr,
                                                 const int* __restrict__ perm) {
    int strp = blockIdx.x & 7;
    int rg   = blockIdx.x >> 3;
    int tr   = threadIdx.x >> 5;           // 0..7: row within block
    int lr   = threadIdx.x & 31;
    __shared__ int   sperm[8];
    __shared__ int   scnt[8];
    __shared__ int   scols[8][ELLW_];
    __shared__ float svals[8][ELLW_];
    if (threadIdx.x < 8) {
        int p = perm[rg * 8 + threadIdx.x];
        sperm[threadIdx.x] = p;
        scnt[threadIdx.x]  = cnt[p];
    }
    __syncthreads();
    {
        int e = threadIdx.x & 63, r0 = threadIdx.x >> 6;      // r0 in 0..3
        int p0 = sperm[r0], p1 = sperm[r0 + 4];
        scols[r0][e] = cols[p0 * ELLW_ + e];     svals[r0][e] = vals[p0 * ELLW_ + e];
        scols[r0 + 4][e] = cols[p1 * ELLW_ + e]; svals[r0 + 4][e] = vals[p1 * ELLW_ + e];
    }
    __syncthreads();
    int i   = sperm[tr];
    int n   = scnt[tr];                      // multiple of 8 (or 0)
    int col = strp * 256 + lr * 8;
    float a[8] = {0, 0, 0, 0, 0, 0, 0, 0};
    for (int e0 = 0; e0 < n; e0 += 8) {
        uint4 q[8];
        float v[8];
#pragma unroll
        for (int u = 0; u < 8; ++u) {
            int c = scols[tr][e0 + u];
            v[u] = svals[tr][e0 + u];
            q[u] = *(const uint4*)(X + (size_t)c * N_ + col);
        }
#pragma unroll
        for (int u = 0; u < 8; ++u) {
            const __half2* h = (const __half2*)&q[u];
            float2 f0 = __half22float2(h[0]), f1 = __half22float2(h[1]);
            float2 f2 = __half22float2(h[2]), f3 = __half22float2(h[3]);
            a[0] -= v[u] * f0.x; a[1] -= v[u] * f0.y;
            a[2] -= v[u] * f1.x; a[3] -= v[u] * f1.y;
            a[4] -= v[u] * f2.x; a[5] -= v[u] * f2.y;
            a[6] -= v[u] * f3.x; a[7] -= v[u] * f3.y;
        }
    }
    size_t po = (size_t)i * N_ + col;
    {   // diagonal term
        float d = dr[i];
        uint4 q = *(const uint4*)(X + po);
        const __half2* h = (const __half2*)&q;
        float2 f0 = __half22float2(h[0]), f1 = __half22float2(h[1]);
        float2 f2 = __half22float2(h[2]), f3 = __half22float2(h[3]);
        a[0] += d * f0.x; a[1] += d * f0.y; a[2] += d * f1.x; a[3] += d * f1.y;
        a[4] += d * f2.x; a[5] += d * f2.y; a[6] += d * f3.x; a[7] += d * f3.y;
    }
    uint4 qp = *(const uint4*)(Tprev + po);
    const __half2* hp = (const __half2*)&qp;
    float2 p0 = __half22float2(hp[0]), p1 = __half22float2(hp[1]);
    float2 p2 = __half22float2(hp[2]), p3 = __half22float2(hp[3]);
    __half2 s0 = __floats2half2_rn(2.f * a[0] - p0.x, 2.f * a[1] - p0.y);
    __half2 s1 = __floats2half2_rn(2.f * a[2] - p1.x, 2.f * a[3] - p1.y);
    __half2 s2 = __floats2half2_rn(2.f * a[4] - p2.x, 2.f * a[5] - p2.y);
    __half2 s3 = __floats2half2_rn(2.f * a[6] - p3.x, 2.f * a[7] - p3.y);
    uint4 sq;
    sq.x = *(const unsigned int*)&s0; sq.y = *(const unsigned int*)&s1;
    sq.z = *(const unsigned int*)&s2; sq.w = *(const unsigned int*)&s3;
    *(uint4*)(Tnext + po) = sq;
}

// ---------------- group reduction: Gh_j += sum_{k in [k0,k0+nslot)} b_{jk} * slot(k%g) -------
__global__ __launch_bounds__(256) void reduce_half(const __half* __restrict__ slots,
                                                   int g, int k0, int nslot, int initG,
                                                   const float* __restrict__ coefs,
                                                   __half* __restrict__ Gh) {
    const size_t NSQ = (size_t)N_ * N_;
    size_t idx = ((size_t)blockIdx.x * 256 + threadIdx.x) * 8;
    __shared__ float sc[J_ * 64];
    for (int x = threadIdx.x; x < J_ * nslot; x += 256) {
        int j = x / nslot, s = x - j * nslot;
        sc[j * 64 + s] = coefs[j * M_ + k0 + s];
    }
    __syncthreads();
    float acc[J_][8];
#pragma unroll
    for (int j = 0; j < J_; ++j) {
        if (initG) {
#pragma unroll
            for (int r = 0; r < 8; ++r) acc[j][r] = 0.f;
        } else {
            uint4 q = *(const uint4*)(Gh + (size_t)j * NSQ + idx);
            const __half2* h = (const __half2*)&q;
            float2 f0 = __half22float2(h[0]), f1 = __half22float2(h[1]);
            float2 f2 = __half22float2(h[2]), f3 = __half22float2(h[3]);
            acc[j][0] = f0.x; acc[j][1] = f0.y; acc[j][2] = f1.x; acc[j][3] = f1.y;
            acc[j][4] = f2.x; acc[j][5] = f2.y; acc[j][6] = f3.x; acc[j][7] = f3.y;
        }
    }
    for (int s = 0; s < nslot; ++s) {
        int slot = (k0 + s) % g;
        uint4 q = *(const uint4*)(slots + (size_t)slot * NSQ + idx);
        const __half2* h = (const __half2*)&q;
        float2 f0 = __half22float2(h[0]), f1 = __half22float2(h[1]);
        float2 f2 = __half22float2(h[2]), f3 = __half22float2(h[3]);
        float f[8] = {f0.x, f0.y, f1.x, f1.y, f2.x, f2.y, f3.x, f3.y};
#pragma unroll
        for (int j = 0; j < J_; ++j) {
            float c = sc[j * 64 + s];
#pragma unroll
            for (int r = 0; r < 8; ++r) acc[j][r] += c * f[r];
        }
    }
#pragma unroll
    for (int j = 0; j < J_; ++j) {
        __half2 o0 = __floats2half2_rn(acc[j][0], acc[j][1]);
        __half2 o1 = __floats2half2_rn(acc[j][2], acc[j][3]);
        __half2 o2 = __floats2half2_rn(acc[j][4], acc[j][5]);
        __half2 o3 = __floats2half2_rn(acc[j][6], acc[j][7]);
        uint4 o;
        o.x = *(const unsigned int*)&o0; o.y = *(const unsigned int*)&o1;
        o.z = *(const unsigned int*)&o2; o.w = *(const unsigned int*)&o3;
        *(uint4*)(Gh + (size_t)j * NSQ + idx) = o;
    }
}

// ---------------- f [2048][256] f32  ->  fhT [256][2048] f16 (transposed) ----------------
__global__ __launch_bounds__(256) void transpose_f16(const float* __restrict__ src,
                                                     __half* __restrict__ dst) {
    int d = blockIdx.x;                    // 256 output rows
    int i0 = threadIdx.x * 8;              // 8 nodes per thread
    __half h[8];
#pragma unroll
    for (int u = 0; u < 8; ++u) h[u] = __float2half(src[(size_t)(i0 + u) * DF_ + d]);
    uint4 o;
    __half2* hp = (__half2*)&o;
    hp[0] = __half2{h[0], h[1]}; hp[1] = __half2{h[2], h[3]};
    hp[2] = __half2{h[4], h[5]}; hp[3] = __half2{h[6], h[7]};
    *(uint4*)(dst + (size_t)d * N_ + i0) = o;
}

// ---------------- MODE-0 MFMA GEMM (128x128): U1T = |Gh * fhT^T|, colsum1 ----------------
// 1D grid 256, XCD-chunked: xcd = bid&7 owns m-chunk [xcd*16, xcd*16+16) x 2 n-tiles.
// (reg-staged form kept unchanged as the control for this round's gload_lds experiment)
__global__ __launch_bounds__(256) void mfma_gemm0(const __half* __restrict__ A,
                                                  const __half* __restrict__ BT,
                                                  __half* __restrict__ U1T,
                                                  float* __restrict__ colsum) {
    __shared__ u16 As[128 * 64];
    __shared__ u16 Bs[128 * 64];
    int bid = blockIdx.x;
    int xcd = bid & 7, t2 = bid >> 3;      // t2 in 0..31
    int mt  = xcd * 16 + (t2 >> 1);        // m-tile 0..127
    int nt  = t2 & 1;                      // n-tile 0..1
    int tid = threadIdx.x;
    int w = tid >> 6, lane = tid & 63;
    int wr = w >> 1, wc = w & 1;
    int gm0 = mt * 128, n0 = nt * 128;
    f32x4 acc[4][4];
#pragma unroll
    for (int mf = 0; mf < 4; ++mf)
#pragma unroll
        for (int nf = 0; nf < 4; ++nf) acc[mf][nf] = (f32x4){0.f, 0.f, 0.f, 0.f};

    int r = tid >> 1, h = tid & 1;
    int sw = r & 7;
    for (int k0 = 0; k0 < 2048; k0 += 64) {
        const u16* ap = (const u16*)A + (size_t)(gm0 + r) * 2048 + k0 + h * 32;
        const u16* bp = (const u16*)BT + (size_t)(n0 + r) * 2048 + k0 + h * 32;
#pragma unroll
        for (int q = 0; q < 4; ++q) {
            int blk = (h * 4 + q) ^ sw;
            *(uint4*)(As + r * 64 + blk * 8) = *(const uint4*)(ap + q * 8);
            *(uint4*)(Bs + r * 64 + blk * 8) = *(const uint4*)(bp + q * 8);
        }
        __syncthreads();
#pragma unroll
        for (int s = 0; s < 2; ++s) {
            f16x8 af[4], bfv[4];
#pragma unroll
            for (int mf = 0; mf < 4; ++mf) {
                int row = wr * 64 + mf * 16 + (lane & 15);
                int blk = (s * 4 + (lane >> 4)) ^ (row & 7);
                af[mf] = *(const f16x8*)(As + row * 64 + blk * 8);
            }
#pragma unroll
            for (int nf = 0; nf < 4; ++nf) {
                int row = wc * 64 + nf * 16 + (lane & 15);
                int blk = (s * 4 + (lane >> 4)) ^ (row & 7);
                bfv[nf] = *(const f16x8*)(Bs + row * 64 + blk * 8);
            }
#pragma unroll
            for (int mf = 0; mf < 4; ++mf)
#pragma unroll
                for (int nf = 0; nf < 4; ++nf)
                    acc[mf][nf] = __builtin_amdgcn_mfma_f32_16x16x32_f16(
                        af[mf], bfv[nf], acc[mf][nf], 0, 0, 0);
        }
        __syncthreads();
    }
    int j = gm0 >> 11;
    int ibase = (gm0 & (N_ - 1)) + wr * 64 + (lane >> 4) * 4;
#pragma unroll
    for (int nf = 0; nf < 4; ++nf) {
        int d = n0 + wc * 64 + nf * 16 + (lane & 15);
        float cs = 0.f;
#pragma unroll
        for (int mf = 0; mf < 4; ++mf) {
            float v0 = fabsf(acc[mf][nf][0]);
            float v1 = fabsf(acc[mf][nf][1]);
            float v2 = fabsf(acc[mf][nf][2]);
            float v3 = fabsf(acc[mf][nf][3]);
            cs += v0 + v1 + v2 + v3;
            ushort4 o;
            o.x = __half_as_ushort(__float2half(v0));
            o.y = __half_as_ushort(__float2half(v1));
            o.z = __half_as_ushort(__float2half(v2));
            o.w = __half_as_ushort(__float2half(v3));
            *(ushort4*)(U1T + (size_t)(j * 256 + d) * N_ + ibase + mf * 16) = o;
        }
        cs += __shfl_xor(cs, 16);
        cs += __shfl_xor(cs, 32);
        if ((lane >> 4) == 0) {
            int colg = n0 + wc * 64 + nf * 16 + lane;
            atomicAdd(&colsum[j * 256 + colg], cs);
        }
    }
}

// ---------------- MODE-1 MFMA GEMM (256x256, 512 threads): colsum2 of |Gh * U1T^T| -------
// XCD-chunked + global_load_lds staging (rule #21: linear LDS dest, inverse-swizzled
// global SOURCE, swizzled read). Wave w stages rows [w*32,+32) in 4 issues of 8 rows;
// lane l covers (row=+l>>3, granule=l&7); source granule = (l&7)^(l>>3) so LDS slot
// (r, gl) holds global granule gl^(r&7) — identical layout to the reg-staged version,
// so the compute/read loop and results are bitwise unchanged.
__global__ __launch_bounds__(512) void gemm256(const __half* __restrict__ A,
                                               const __half* __restrict__ BT,
                                               float* __restrict__ colsum) {
    __shared__ u16 As[256 * 64];
    __shared__ u16 Bs[256 * 64];
    int bid = blockIdx.x;
    int xcd = bid & 7, t2 = bid >> 3;      // t2 in 0..63
    int mt  = xcd * 8 + (t2 >> 3);         // m-tile 0..63
    int nt  = t2 & 7;                      // n-tile 0..7
    int tid = threadIdx.x;
    int w = tid >> 6, lane = tid & 63;
    int wr = w >> 2, wc = w & 3;           // 2 x 4 waves; per-wave tile 128m x 64n
    int gm0 = mt * 256, n0 = nt * 256;
    f32x4 acc[8][4];
#pragma unroll
    for (int mf = 0; mf < 8; ++mf)
#pragma unroll
        for (int nf = 0; nf < 4; ++nf) acc[mf][nf] = (f32x4){0.f, 0.f, 0.f, 0.f};

    // staging geometry (per wave-issue): row r2 = w*32 + q*8 + (lane>>3), granule lane&7
    int lrow = lane >> 3;                  // 0..7
    int gsrc = (lane & 7) ^ lrow;          // inverse-swizzled source granule
    const u16* gaBase = (const u16*)A + (size_t)(gm0 + w * 32 + lrow) * 2048 + gsrc * 8;
    const u16* gbBase = (const u16*)BT + (size_t)(n0 + w * 32 + lrow) * 2048 + gsrc * 8;

    for (int k0 = 0; k0 < 2048; k0 += 64) {
#pragma unroll
        for (int q = 0; q < 4; ++q) {
            const u16* ga = gaBase + (size_t)(q * 8) * 2048 + k0;
            const u16* gb = gbBase + (size_t)(q * 8) * 2048 + k0;
            u16* la = As + (w * 32 + q * 8) * 64;   // wave-uniform LDS base
            u16* lb = Bs + (w * 32 + q * 8) * 64;
            __builtin_amdgcn_global_load_lds((glb_u32*)ga, (lds_u32*)la, 16, 0, 0);
            __builtin_amdgcn_global_load_lds((glb_u32*)gb, (lds_u32*)lb, 16, 0, 0);
        }
        __syncthreads();
#pragma unroll
        for (int s = 0; s < 2; ++s) {
            f16x8 af[8], bfv[4];
#pragma unroll
            for (int mf = 0; mf < 8; ++mf) {
                int row = wr * 128 + mf * 16 + (lane & 15);
                int blk = (s * 4 + (lane >> 4)) ^ (row & 7);
                af[mf] = *(const f16x8*)(As + row * 64 + blk * 8);
            }
#pragma unroll
            for (int nf = 0; nf < 4; ++nf) {
                int row = wc * 64 + nf * 16 + (lane & 15);
                int blk = (s * 4 + (lane >> 4)) ^ (row & 7);
                bfv[nf] = *(const f16x8*)(Bs + row * 64 + blk * 8);
            }
#pragma unroll
            for (int mf = 0; mf < 8; ++mf)
#pragma unroll
                for (int nf = 0; nf < 4; ++nf)
                    acc[mf][nf] = __builtin_amdgcn_mfma_f32_16x16x32_f16(
                        af[mf], bfv[nf], acc[mf][nf], 0, 0, 0);
        }
        __syncthreads();
    }
    int j = gm0 >> 11;                     // 256-row m-tile never spans a j boundary
#pragma unroll
    for (int nf = 0; nf < 4; ++nf) {
        float cs = 0.f;
#pragma unroll
        for (int mf = 0; mf < 8; ++mf) {
            cs += fabsf(acc[mf][nf][0]) + fabsf(acc[mf][nf][1])
                + fabsf(acc[mf][nf][2]) + fabsf(acc[mf][nf][3]);
        }
        cs += __shfl_xor(cs, 16);
        cs += __shfl_xor(cs, 32);
        if ((lane >> 4) == 0) {
            int colg = n0 + wc * 64 + nf * 16 + lane;
            atomicAdd(&colsum[(((colg >> 8) * 8 + j) << 8) + (colg & 255)], cs);
        }
    }
}

__global__ __launch_bounds__(256) void fmean_kernel(const float* __restrict__ f, float* __restrict__ out) {
    int d = blockIdx.x, t = threadIdx.x;
    float s = 0.f;
    for (int n = t; n < N_; n += 256) s += f[(size_t)n * DF_ + d];
    __shared__ float red[256];
    red[t] = s; __syncthreads();
    for (int o = 128; o; o >>= 1) { if (t < o) red[t] += red[t + o]; __syncthreads(); }
    if (t == 0) out[d] = red[0] * (1.f / N_);
}

__global__ __launch_bounds__(256) void finalize_kernel(const float* __restrict__ sum1,
                                                       const float* __restrict__ sum2,
                                                       float* __restrict__ out) {
    int idx = blockIdx.x * 256 + threadIdx.x;
    if (idx < 2048)  out[256 + idx]  = sum1[idx] * (1.f / N_);
    if (idx < 16384) out[2304 + idx] = sum2[idx] * (1.f / N_);
}

// ---------------- host orchestration ----------------
extern "C" void kernel_launch(void* const* d_in, const int* in_sizes, int n_in,
                              void* d_out, int out_size, void* d_ws, size_t ws_size,
                              hipStream_t stream) {
    (void)in_sizes; (void)n_in;
    const float* W = (const float*)d_in[0];
    const float* f = (const float*)d_in[1];
    float* out = (float*)d_out;
    char* base = (char*)d_ws;
    size_t off = 0;
    auto take = [&](size_t bytes) -> char* {
        off = (off + 255) & ~(size_t)255;
        char* p = base + off; off += bytes; return p;
    };
    const size_t NSQ = (size_t)N_ * N_;
    float*  dh    = (float*)take((size_t)N_ * 4);
    float*  dr    = (float*)take((size_t)N_ * 4);
    int*    cnt   = (int*)take((size_t)N_ * 4);
    int*    perm  = (int*)take((size_t)N_ * 4);
    int*    cols  = (int*)take((size_t)N_ * ELLW_ * 4);
    float*  vals  = (float*)take((size_t)N_ * ELLW_ * 4);
    float*  coefs = (float*)take((size_t)J_ * M_ * 4);
    float*  sum1  = (float*)take(2048 * 4);
    float*  sum2  = (float*)take(16384 * 4);
    __half* Gh    = (__half*)take(NSQ * 2 * J_);                 //  67.1 MB
    __half* U1T   = (__half*)take((size_t)N_ * 2048 * 2);        //   8.4 MB
    __half* fhT   = (__half*)take((size_t)N_ * DF_ * 2);         //   1.0 MB
    off = (off + 255) & ~(size_t)255;
    const size_t slotBytes = NSQ * 2;
    long long rem = (long long)ws_size - (long long)off;
    int g = (int)(rem / (long long)slotBytes);
    if (g > GCAP_) g = GCAP_;
    if (g < 3) {                       // workspace too small — cannot run
        hipMemsetAsync(d_out, 0, (size_t)out_size * 4, stream);
        return;
    }
    __half* slots = (__half*)take((size_t)g * slotBytes);

    deg_kernel<<<N_, 256, 0, stream>>>(W, dh, dr);
    ell_kernel<<<N_, 64, 0, stream>>>(W, dh, cnt, cols, vals);
    perm_kernel<<<1, 256, 0, stream>>>(cnt, perm);
    coef_kernel<<<64, 256, 0, stream>>>(coefs);
    hipMemsetAsync(sum1, 0, 2048 * 4, stream);
    hipMemsetAsync(sum2, 0, 16384 * 4, stream);
    init_slots<<<N_, 256, 0, stream>>>(slots, slots + NSQ, cnt, cols, vals, dr);

    int k0 = 0;                        // start of current un-reduced group
    for (int k = 2; k < MUSE_; ++k) {
        cheb_fp16<<<2048, 256, 0, stream>>>(
            slots + (size_t)((k - 1) % g) * NSQ,
            slots + (size_t)((k - 2) % g) * NSQ,
            slots + (size_t)(k % g) * NSQ,
            cnt, cols, vals, dr, perm);
        if (k - k0 + 1 == g || k == MUSE_ - 1) {
            reduce_half<<<2048, 256, 0, stream>>>(slots, g, k0, k - k0 + 1,
                                                  k0 == 0 ? 1 : 0, coefs, Gh);
            k0 = k + 1;
        }
    }
    transpose_f16<<<DF_, 256, 0, stream>>>(f, fhT);
    mfma_gemm0<<<256, 256, 0, stream>>>(Gh, fhT, U1T, sum1);
    gemm256<<<512, 512, 0, stream>>>(Gh, U1T, sum2);
    fmean_kernel<<<DF_, 256, 0, stream>>>(f, out);
    finalize_kernel<<<64, 256, 0, stream>>>(sum1, sum2, out);
}

// Round 16
// 692.554 us; speedup vs baseline: 1.7599x; 1.2104x over previous
//
#include <hip/hip_runtime.h>
#include <hip/hip_fp16.h>
#include <math.h>

// ---------------- constants ----------------
constexpr int   N_   = 2048;
constexpr int   DF_  = 256;
constexpr int   J_   = 8;
constexpr int   ELLW_= 64;
constexpr int   M_   = 256;          // coefficient array stride (256-pt DCT quadrature)
constexpr int   MUSE_= 32;           // Chebyshev terms actually used (degree 31)
constexpr int   GCAP_= 11;           // ring 92MB; exactly 3 reduce passes (11+11+10)
constexpr float H_   = 1.01f;        // domain half-width  ([-0.01, 2.01])
constexpr float C0_  = 1.0f;         // domain center
constexpr float AF_  = 0.34657359027997264f;   // A = 3*ln(2)/6
constexpr float PI_F = 3.14159265358979323846f;

typedef _Float16 f16x8 __attribute__((ext_vector_type(8)));
typedef __attribute__((ext_vector_type(4))) float f32x4;
using u16 = unsigned short;
typedef __attribute__((address_space(3))) unsigned int lds_u32;
typedef const __attribute__((address_space(1))) unsigned int glb_u32;

// ---------------- filter functions ----------------
__device__ __forceinline__ float g_hat_f(float x) {
    float val = 0.5f + 0.5f * cosf(2.f * PI_F * (x / AF_ + 0.5f));
    return (x <= 0.f && x > -AF_) ? val : 0.f;
}
__device__ __forceinline__ float wavelet_f(float lamb, int j) {
    float lmin = expf(AF_ * ((j - 1) / 3.0f - 1.0f));
    float lam  = fmaxf(lamb, lmin);
    return g_hat_f(logf(lam) - AF_ * (j - 1) / 3.0f);
}
__device__ __forceinline__ float filter_eval(float lamb, int jf) {
    if (jf == 0) {
        float g3 = 0.f;
        for (int j = 2; j <= 8; ++j) { float w = wavelet_f(lamb, j); g3 += w * w; }
        return sqrtf(fmaxf(1.5f - g3, 0.f));
    }
    return wavelet_f(lamb, jf + 1);
}

// ---------------- setup kernels ----------------
__global__ __launch_bounds__(256) void deg_kernel(const float* __restrict__ W,
                                                  float* __restrict__ dh,
                                                  float* __restrict__ dr) {
    int i = blockIdx.x, t = threadIdx.x;
    const float4* row = (const float4*)(W + (size_t)i * N_);
    float s = 0.f;
    for (int c = t; c < N_ / 4; c += 256) { float4 v = row[c]; s += v.x + v.y + v.z + v.w; }
    __shared__ float red[256];
    red[t] = s; __syncthreads();
    for (int o = 128; o; o >>= 1) { if (t < o) red[t] += red[t + o]; __syncthreads(); }
    if (t == 0) {
        float deg = red[0];
        float dhi = 1.f / sqrtf(fmaxf(deg, 1.f));
        dh[i] = dhi;
        dr[i] = (dhi * dhi * deg - C0_) / H_;
    }
}

// ELL build: all 64 entries pre-filled with (col=i, val=0) pads; cnt rounded up to mult of 8.
__global__ __launch_bounds__(64) void ell_kernel(const float* __restrict__ W,
                                                 const float* __restrict__ dh,
                                                 int* __restrict__ cnt,
                                                 int* __restrict__ cols,
                                                 float* __restrict__ vals) {
    int i = blockIdx.x, lane = threadIdx.x;
    cols[i * ELLW_ + lane] = i;            // pad defaults
    vals[i * ELLW_ + lane] = 0.f;
    __syncthreads();
    const float* row = W + (size_t)i * N_;
    unsigned long long lt = (1ull << lane) - 1ull;
    int base = 0;
    float dhi = dh[i];
    for (int c = 0; c < N_; c += 64) {
        float v = row[c + lane];
        unsigned long long m = __ballot(v != 0.f);
        if (v != 0.f) {
            int pos = base + __popcll(m & lt);
            if (pos < ELLW_) {
                cols[i * ELLW_ + pos] = c + lane;
                vals[i * ELLW_ + pos] = dhi * dh[c + lane] / H_;
            }
        }
        base += __popcll(m);
    }
    if (lane == 0) {
        int n = base < ELLW_ ? base : ELLW_;
        cnt[i] = (n + 7) & ~7;             // padded count (pads are no-ops)
    }
}

// deterministic counting sort of rows by padded degree -> perm (parallel scan version)
__global__ __launch_bounds__(256) void perm_kernel(const int* __restrict__ cnt,
                                                   int* __restrict__ perm) {
    __shared__ int hist[9][256];           // per-thread bucket counts -> exclusive offsets
    __shared__ int bstart[9];
    int t = threadIdx.x;
    int b[8];
    int h[9] = {0, 0, 0, 0, 0, 0, 0, 0, 0};
#pragma unroll
    for (int u = 0; u < 8; ++u) {
        b[u] = cnt[t * 8 + u] >> 3;        // bucket 0..8
        h[b[u]]++;
    }
#pragma unroll
    for (int bb = 0; bb < 9; ++bb) hist[bb][t] = h[bb];
    __syncthreads();
    if (t < 9) {                           // exclusive scan across threads, per bucket
        int acc = 0;
        for (int k = 0; k < 256; ++k) { int v = hist[t][k]; hist[t][k] = acc; acc += v; }
        bstart[t] = acc;                   // bucket total
    }
    __syncthreads();
    if (t == 0) {                          // exclusive scan of bucket totals
        int acc = 0;
        for (int bb = 0; bb < 9; ++bb) { int v = bstart[bb]; bstart[bb] = acc; acc += v; }
    }
    __syncthreads();
    int run[9] = {0, 0, 0, 0, 0, 0, 0, 0, 0};
#pragma unroll
    for (int u = 0; u < 8; ++u) {
        int bb = b[u];
        perm[bstart[bb] + hist[bb][t] + run[bb]] = t * 8 + u;
        run[bb]++;
    }
}

// parallel DCT: 64 blocks = 8 filters x 8 output-chunks; 8 threads per output.
__global__ __launch_bounds__(256) void coef_kernel(float* __restrict__ coefs) {
    __shared__ float fv[M_];
    int j     = blockIdx.x >> 3;
    int chunk = blockIdx.x & 7;
    int t = threadIdx.x;
    float theta = PI_F * (t + 0.5f) / M_;
    fv[t] = filter_eval(C0_ + H_ * cosf(theta), j);
    __syncthreads();
    int out = chunk * 32 + (t >> 3);       // output index 0..255
    int seg = t & 7;                       // 8 threads per output
    float s = 0.f;
    for (int i = seg * 32; i < seg * 32 + 32; ++i)
        s += fv[i] * cosf(PI_F * out * (i + 0.5f) / M_);
    s += __shfl_xor(s, 1);
    s += __shfl_xor(s, 2);
    s += __shfl_xor(s, 4);
    if (seg == 0) coefs[j * M_ + out] = s * ((out == 0 ? 1.f : 2.f) / M_);
}

// slot0 = I (fp16), slot1 = scaled L-tilde (fp16)
__global__ __launch_bounds__(256) void init_slots(__half* __restrict__ S0, __half* __restrict__ S1,
                                                  const int* __restrict__ cnt, const int* __restrict__ cols,
                                                  const float* __restrict__ vals, const float* __restrict__ dr) {
    int i = blockIdx.x, t = threadIdx.x;
    size_t ro = (size_t)i * N_;
    for (int c = t * 8; c < N_; c += 2048) {
        *(uint4*)(S0 + ro + c) = uint4{0, 0, 0, 0};
        *(uint4*)(S1 + ro + c) = uint4{0, 0, 0, 0};
    }
    __syncthreads();
    int n = cnt[i];
    if (t < n) {
        int c = cols[i * ELLW_ + t];
        float v = -vals[i * ELLW_ + t];
        if (v != 0.f) S1[ro + c] = __float2half(v);   // skip pads (col=i, val=0)
    }
    __syncthreads();
    if (t == 0) {
        S0[ro + i] = __float2half(1.f);
        S1[ro + i] = __float2half(dr[i]);
    }
}

// ------- Chebyshev step, XCD-striped + degree-sorted rows (proven R8 form: unroll-8) -----
__global__ __launch_bounds__(256) void cheb_fp16(const __half* __restrict__ X,
                                                 const __half* __restrict__ Tprev,
                                                 __half* __restrict__ Tnext,
                                                 const int* __restrict__ cnt,
                                                 const int* __restrict__ cols,
                                                 const float* __restrict__ vals,
                                                 const float* __restrict__ dr,
                                                 const int* __restrict__ perm) {
    int strp = blockIdx.x & 7;
    int rg   = blockIdx.x >> 3;
    int tr   = threadIdx.x >> 5;           // 0..7: row within block
    int lr   = threadIdx.x & 31;
    __shared__ int   sperm[8];
    __shared__ int   scnt[8];
    __shared__ int   scols[8][ELLW_];
    __shared__ float svals[8][ELLW_];
    if (threadIdx.x < 8) {
        int p = perm[rg * 8 + threadIdx.x];
        sperm[threadIdx.x] = p;
        scnt[threadIdx.x]  = cnt[p];
    }
    __syncthreads();
    {
        int e = threadIdx.x & 63, r0 = threadIdx.x >> 6;      // r0 in 0..3
        int p0 = sperm[r0], p1 = sperm[r0 + 4];
        scols[r0][e] = cols[p0 * ELLW_ + e];     svals[r0][e] = vals[p0 * ELLW_ + e];
        scols[r0 + 4][e] = cols[p1 * ELLW_ + e]; svals[r0 + 4][e] = vals[p1 * ELLW_ + e];
    }
    __syncthreads();
    int i   = sperm[tr];
    int n   = scnt[tr];                      // multiple of 8 (or 0)
    int col = strp * 256 + lr * 8;
    float a[8] = {0, 0, 0, 0, 0, 0, 0, 0};
    for (int e0 = 0; e0 < n; e0 += 8) {
        uint4 q[8];
        float v[8];
#pragma unroll
        for (int u = 0; u < 8; ++u) {
            int c = scols[tr][e0 + u];
            v[u] = svals[tr][e0 + u];
            q[u] = *(const uint4*)(X + (size_t)c * N_ + col);
        }
#pragma unroll
        for (int u = 0; u < 8; ++u) {
            const __half2* h = (const __half2*)&q[u];
            float2 f0 = __half22float2(h[0]), f1 = __half22float2(h[1]);
            float2 f2 = __half22float2(h[2]), f3 = __half22float2(h[3]);
            a[0] -= v[u] * f0.x; a[1] -= v[u] * f0.y;
            a[2] -= v[u] * f1.x; a[3] -= v[u] * f1.y;
            a[4] -= v[u] * f2.x; a[5] -= v[u] * f2.y;
            a[6] -= v[u] * f3.x; a[7] -= v[u] * f3.y;
        }
    }
    size_t po = (size_t)i * N_ + col;
    {   // diagonal term
        float d = dr[i];
        uint4 q = *(const uint4*)(X + po);
        const __half2* h = (const __half2*)&q;
        float2 f0 = __half22float2(h[0]), f1 = __half22float2(h[1]);
        float2 f2 = __half22float2(h[2]), f3 = __half22float2(h[3]);
        a[0] += d * f0.x; a[1] += d * f0.y; a[2] += d * f1.x; a[3] += d * f1.y;
        a[4] += d * f2.x; a[5] += d * f2.y; a[6] += d * f3.x; a[7] += d * f3.y;
    }
    uint4 qp = *(const uint4*)(Tprev + po);
    const __half2* hp = (const __half2*)&qp;
    float2 p0 = __half22float2(hp[0]), p1 = __half22float2(hp[1]);
    float2 p2 = __half22float2(hp[2]), p3 = __half22float2(hp[3]);
    __half2 s0 = __floats2half2_rn(2.f * a[0] - p0.x, 2.f * a[1] - p0.y);
    __half2 s1 = __floats2half2_rn(2.f * a[2] - p1.x, 2.f * a[3] - p1.y);
    __half2 s2 = __floats2half2_rn(2.f * a[4] - p2.x, 2.f * a[5] - p2.y);
    __half2 s3 = __floats2half2_rn(2.f * a[6] - p3.x, 2.f * a[7] - p3.y);
    uint4 sq;
    sq.x = *(const unsigned int*)&s0; sq.y = *(const unsigned int*)&s1;
    sq.z = *(const unsigned int*)&s2; sq.w = *(const unsigned int*)&s3;
    *(uint4*)(Tnext + po) = sq;
}

// ---------------- group reduction: Gh_j += sum_{k in [k0,k0+nslot)} b_{jk} * slot(k%g) -------
__global__ __launch_bounds__(256) void reduce_half(const __half* __restrict__ slots,
                                                   int g, int k0, int nslot, int initG,
                                                   const float* __restrict__ coefs,
                                                   __half* __restrict__ Gh) {
    const size_t NSQ = (size_t)N_ * N_;
    size_t idx = ((size_t)blockIdx.x * 256 + threadIdx.x) * 8;
    __shared__ float sc[J_ * 64];
    for (int x = threadIdx.x; x < J_ * nslot; x += 256) {
        int j = x / nslot, s = x - j * nslot;
        sc[j * 64 + s] = coefs[j * M_ + k0 + s];
    }
    __syncthreads();
    float acc[J_][8];
#pragma unroll
    for (int j = 0; j < J_; ++j) {
        if (initG) {
#pragma unroll
            for (int r = 0; r < 8; ++r) acc[j][r] = 0.f;
        } else {
            uint4 q = *(const uint4*)(Gh + (size_t)j * NSQ + idx);
            const __half2* h = (const __half2*)&q;
            float2 f0 = __half22float2(h[0]), f1 = __half22float2(h[1]);
            float2 f2 = __half22float2(h[2]), f3 = __half22float2(h[3]);
            acc[j][0] = f0.x; acc[j][1] = f0.y; acc[j][2] = f1.x; acc[j][3] = f1.y;
            acc[j][4] = f2.x; acc[j][5] = f2.y; acc[j][6] = f3.x; acc[j][7] = f3.y;
        }
    }
    for (int s = 0; s < nslot; ++s) {
        int slot = (k0 + s) % g;
        uint4 q = *(const uint4*)(slots + (size_t)slot * NSQ + idx);
        const __half2* h = (const __half2*)&q;
        float2 f0 = __half22float2(h[0]), f1 = __half22float2(h[1]);
        float2 f2 = __half22float2(h[2]), f3 = __half22float2(h[3]);
        float f[8] = {f0.x, f0.y, f1.x, f1.y, f2.x, f2.y, f3.x, f3.y};
#pragma unroll
        for (int j = 0; j < J_; ++j) {
            float c = sc[j * 64 + s];
#pragma unroll
            for (int r = 0; r < 8; ++r) acc[j][r] += c * f[r];
        }
    }
#pragma unroll
    for (int j = 0; j < J_; ++j) {
        __half2 o0 = __floats2half2_rn(acc[j][0], acc[j][1]);
        __half2 o1 = __floats2half2_rn(acc[j][2], acc[j][3]);
        __half2 o2 = __floats2half2_rn(acc[j][4], acc[j][5]);
        __half2 o3 = __floats2half2_rn(acc[j][6], acc[j][7]);
        uint4 o;
        o.x = *(const unsigned int*)&o0; o.y = *(const unsigned int*)&o1;
        o.z = *(const unsigned int*)&o2; o.w = *(const unsigned int*)&o3;
        *(uint4*)(Gh + (size_t)j * NSQ + idx) = o;
    }
}

// ---------------- f [2048][256] f32  ->  fhT [256][2048] f16 (transposed) ----------------
__global__ __launch_bounds__(256) void transpose_f16(const float* __restrict__ src,
                                                     __half* __restrict__ dst) {
    int d = blockIdx.x;                    // 256 output rows
    int i0 = threadIdx.x * 8;              // 8 nodes per thread
    __half h[8];
#pragma unroll
    for (int u = 0; u < 8; ++u) h[u] = __float2half(src[(size_t)(i0 + u) * DF_ + d]);
    uint4 o;
    __half2* hp = (__half2*)&o;
    hp[0] = __half2{h[0], h[1]}; hp[1] = __half2{h[2], h[3]};
    hp[2] = __half2{h[4], h[5]}; hp[3] = __half2{h[6], h[7]};
    *(uint4*)(dst + (size_t)d * N_ + i0) = o;
}

// ---------------- MODE-0 MFMA GEMM (128x128): U1T = |Gh * fhT^T|, colsum1 ----------------
// 1D grid 256, XCD-chunked; global_load_lds staging (same involution as gemm256):
// wave w stages rows [w*32,+32) in 4 issues; lane l -> row +l>>3, source granule (l&7)^(l>>3).
__global__ __launch_bounds__(256) void mfma_gemm0(const __half* __restrict__ A,
                                                  const __half* __restrict__ BT,
                                                  __half* __restrict__ U1T,
                                                  float* __restrict__ colsum) {
    __shared__ u16 As[128 * 64];
    __shared__ u16 Bs[128 * 64];
    int bid = blockIdx.x;
    int xcd = bid & 7, t2 = bid >> 3;      // t2 in 0..31
    int mt  = xcd * 16 + (t2 >> 1);        // m-tile 0..127
    int nt  = t2 & 1;                      // n-tile 0..1
    int tid = threadIdx.x;
    int w = tid >> 6, lane = tid & 63;     // 4 waves, each stages 32 rows
    int wr = w >> 1, wc = w & 1;
    int gm0 = mt * 128, n0 = nt * 128;
    f32x4 acc[4][4];
#pragma unroll
    for (int mf = 0; mf < 4; ++mf)
#pragma unroll
        for (int nf = 0; nf < 4; ++nf) acc[mf][nf] = (f32x4){0.f, 0.f, 0.f, 0.f};

    int lrow = lane >> 3;                  // 0..7
    int gsrc = (lane & 7) ^ lrow;          // inverse-swizzled source granule
    const u16* gaBase = (const u16*)A + (size_t)(gm0 + w * 32 + lrow) * 2048 + gsrc * 8;
    const u16* gbBase = (const u16*)BT + (size_t)(n0 + w * 32 + lrow) * 2048 + gsrc * 8;

    for (int k0 = 0; k0 < 2048; k0 += 64) {
#pragma unroll
        for (int q = 0; q < 4; ++q) {
            const u16* ga = gaBase + (size_t)(q * 8) * 2048 + k0;
            const u16* gb = gbBase + (size_t)(q * 8) * 2048 + k0;
            u16* la = As + (w * 32 + q * 8) * 64;   // wave-uniform LDS base
            u16* lb = Bs + (w * 32 + q * 8) * 64;
            __builtin_amdgcn_global_load_lds((glb_u32*)ga, (lds_u32*)la, 16, 0, 0);
            __builtin_amdgcn_global_load_lds((glb_u32*)gb, (lds_u32*)lb, 16, 0, 0);
        }
        __syncthreads();
#pragma unroll
        for (int s = 0; s < 2; ++s) {
            f16x8 af[4], bfv[4];
#pragma unroll
            for (int mf = 0; mf < 4; ++mf) {
                int row = wr * 64 + mf * 16 + (lane & 15);
                int blk = (s * 4 + (lane >> 4)) ^ (row & 7);
                af[mf] = *(const f16x8*)(As + row * 64 + blk * 8);
            }
#pragma unroll
            for (int nf = 0; nf < 4; ++nf) {
                int row = wc * 64 + nf * 16 + (lane & 15);
                int blk = (s * 4 + (lane >> 4)) ^ (row & 7);
                bfv[nf] = *(const f16x8*)(Bs + row * 64 + blk * 8);
            }
#pragma unroll
            for (int mf = 0; mf < 4; ++mf)
#pragma unroll
                for (int nf = 0; nf < 4; ++nf)
                    acc[mf][nf] = __builtin_amdgcn_mfma_f32_16x16x32_f16(
                        af[mf], bfv[nf], acc[mf][nf], 0, 0, 0);
        }
        __syncthreads();
    }
    int j = gm0 >> 11;
    int ibase = (gm0 & (N_ - 1)) + wr * 64 + (lane >> 4) * 4;
#pragma unroll
    for (int nf = 0; nf < 4; ++nf) {
        int d = n0 + wc * 64 + nf * 16 + (lane & 15);
        float cs = 0.f;
#pragma unroll
        for (int mf = 0; mf < 4; ++mf) {
            float v0 = fabsf(acc[mf][nf][0]);
            float v1 = fabsf(acc[mf][nf][1]);
            float v2 = fabsf(acc[mf][nf][2]);
            float v3 = fabsf(acc[mf][nf][3]);
            cs += v0 + v1 + v2 + v3;
            ushort4 o;
            o.x = __half_as_ushort(__float2half(v0));
            o.y = __half_as_ushort(__float2half(v1));
            o.z = __half_as_ushort(__float2half(v2));
            o.w = __half_as_ushort(__float2half(v3));
            *(ushort4*)(U1T + (size_t)(j * 256 + d) * N_ + ibase + mf * 16) = o;
        }
        cs += __shfl_xor(cs, 16);
        cs += __shfl_xor(cs, 32);
        if ((lane >> 4) == 0) {
            int colg = n0 + wc * 64 + nf * 16 + lane;
            atomicAdd(&colsum[j * 256 + colg], cs);
        }
    }
}

// ---------------- MODE-1 MFMA GEMM (256x256, 512 threads): colsum2 of |Gh * U1T^T| -------
// XCD-chunked + global_load_lds staging (rule #21: linear LDS dest, inverse-swizzled
// global SOURCE, swizzled read).
__global__ __launch_bounds__(512) void gemm256(const __half* __restrict__ A,
                                               const __half* __restrict__ BT,
                                               float* __restrict__ colsum) {
    __shared__ u16 As[256 * 64];
    __shared__ u16 Bs[256 * 64];
    int bid = blockIdx.x;
    int xcd = bid & 7, t2 = bid >> 3;      // t2 in 0..63
    int mt  = xcd * 8 + (t2 >> 3);         // m-tile 0..63
    int nt  = t2 & 7;                      // n-tile 0..7
    int tid = threadIdx.x;
    int w = tid >> 6, lane = tid & 63;
    int wr = w >> 2, wc = w & 3;           // 2 x 4 waves; per-wave tile 128m x 64n
    int gm0 = mt * 256, n0 = nt * 256;
    f32x4 acc[8][4];
#pragma unroll
    for (int mf = 0; mf < 8; ++mf)
#pragma unroll
        for (int nf = 0; nf < 4; ++nf) acc[mf][nf] = (f32x4){0.f, 0.f, 0.f, 0.f};

    int lrow = lane >> 3;                  // 0..7
    int gsrc = (lane & 7) ^ lrow;          // inverse-swizzled source granule
    const u16* gaBase = (const u16*)A + (size_t)(gm0 + w * 32 + lrow) * 2048 + gsrc * 8;
    const u16* gbBase = (const u16*)BT + (size_t)(n0 + w * 32 + lrow) * 2048 + gsrc * 8;

    for (int k0 = 0; k0 < 2048; k0 += 64) {
#pragma unroll
        for (int q = 0; q < 4; ++q) {
            const u16* ga = gaBase + (size_t)(q * 8) * 2048 + k0;
            const u16* gb = gbBase + (size_t)(q * 8) * 2048 + k0;
            u16* la = As + (w * 32 + q * 8) * 64;   // wave-uniform LDS base
            u16* lb = Bs + (w * 32 + q * 8) * 64;
            __builtin_amdgcn_global_load_lds((glb_u32*)ga, (lds_u32*)la, 16, 0, 0);
            __builtin_amdgcn_global_load_lds((glb_u32*)gb, (lds_u32*)lb, 16, 0, 0);
        }
        __syncthreads();
#pragma unroll
        for (int s = 0; s < 2; ++s) {
            f16x8 af[8], bfv[4];
#pragma unroll
            for (int mf = 0; mf < 8; ++mf) {
                int row = wr * 128 + mf * 16 + (lane & 15);
                int blk = (s * 4 + (lane >> 4)) ^ (row & 7);
                af[mf] = *(const f16x8*)(As + row * 64 + blk * 8);
            }
#pragma unroll
            for (int nf = 0; nf < 4; ++nf) {
                int row = wc * 64 + nf * 16 + (lane & 15);
                int blk = (s * 4 + (lane >> 4)) ^ (row & 7);
                bfv[nf] = *(const f16x8*)(Bs + row * 64 + blk * 8);
            }
#pragma unroll
            for (int mf = 0; mf < 8; ++mf)
#pragma unroll
                for (int nf = 0; nf < 4; ++nf)
                    acc[mf][nf] = __builtin_amdgcn_mfma_f32_16x16x32_f16(
                        af[mf], bfv[nf], acc[mf][nf], 0, 0, 0);
        }
        __syncthreads();
    }
    int j = gm0 >> 11;                     // 256-row m-tile never spans a j boundary
#pragma unroll
    for (int nf = 0; nf < 4; ++nf) {
        float cs = 0.f;
#pragma unroll
        for (int mf = 0; mf < 8; ++mf) {
            cs += fabsf(acc[mf][nf][0]) + fabsf(acc[mf][nf][1])
                + fabsf(acc[mf][nf][2]) + fabsf(acc[mf][nf][3]);
        }
        cs += __shfl_xor(cs, 16);
        cs += __shfl_xor(cs, 32);
        if ((lane >> 4) == 0) {
            int colg = n0 + wc * 64 + nf * 16 + lane;
            atomicAdd(&colsum[(((colg >> 8) * 8 + j) << 8) + (colg & 255)], cs);
        }
    }
}

__global__ __launch_bounds__(256) void fmean_kernel(const float* __restrict__ f, float* __restrict__ out) {
    int d = blockIdx.x, t = threadIdx.x;
    float s = 0.f;
    for (int n = t; n < N_; n += 256) s += f[(size_t)n * DF_ + d];
    __shared__ float red[256];
    red[t] = s; __syncthreads();
    for (int o = 128; o; o >>= 1) { if (t < o) red[t] += red[t + o]; __syncthreads(); }
    if (t == 0) out[d] = red[0] * (1.f / N_);
}

__global__ __launch_bounds__(256) void finalize_kernel(const float* __restrict__ sum1,
                                                       const float* __restrict__ sum2,
                                                       float* __restrict__ out) {
    int idx = blockIdx.x * 256 + threadIdx.x;
    if (idx < 2048)  out[256 + idx]  = sum1[idx] * (1.f / N_);
    if (idx < 16384) out[2304 + idx] = sum2[idx] * (1.f / N_);
}

// ---------------- host orchestration ----------------
extern "C" void kernel_launch(void* const* d_in, const int* in_sizes, int n_in,
                              void* d_out, int out_size, void* d_ws, size_t ws_size,
                              hipStream_t stream) {
    (void)in_sizes; (void)n_in;
    const float* W = (const float*)d_in[0];
    const float* f = (const float*)d_in[1];
    float* out = (float*)d_out;
    char* base = (char*)d_ws;
    size_t off = 0;
    auto take = [&](size_t bytes) -> char* {
        off = (off + 255) & ~(size_t)255;
        char* p = base + off; off += bytes; return p;
    };
    const size_t NSQ = (size_t)N_ * N_;
    float*  dh    = (float*)take((size_t)N_ * 4);
    float*  dr    = (float*)take((size_t)N_ * 4);
    int*    cnt   = (int*)take((size_t)N_ * 4);
    int*    perm  = (int*)take((size_t)N_ * 4);
    int*    cols  = (int*)take((size_t)N_ * ELLW_ * 4);
    float*  vals  = (float*)take((size_t)N_ * ELLW_ * 4);
    float*  coefs = (float*)take((size_t)J_ * M_ * 4);
    float*  sum1  = (float*)take(2048 * 4);
    float*  sum2  = (float*)take(16384 * 4);
    __half* Gh    = (__half*)take(NSQ * 2 * J_);                 //  67.1 MB
    __half* U1T   = (__half*)take((size_t)N_ * 2048 * 2);        //   8.4 MB
    __half* fhT   = (__half*)take((size_t)N_ * DF_ * 2);         //   1.0 MB
    off = (off + 255) & ~(size_t)255;
    const size_t slotBytes = NSQ * 2;
    long long rem = (long long)ws_size - (long long)off;
    int g = (int)(rem / (long long)slotBytes);
    if (g > GCAP_) g = GCAP_;
    if (g < 3) {                       // workspace too small — cannot run
        hipMemsetAsync(d_out, 0, (size_t)out_size * 4, stream);
        return;
    }
    __half* slots = (__half*)take((size_t)g * slotBytes);

    deg_kernel<<<N_, 256, 0, stream>>>(W, dh, dr);
    ell_kernel<<<N_, 64, 0, stream>>>(W, dh, cnt, cols, vals);
    perm_kernel<<<1, 256, 0, stream>>>(cnt, perm);
    coef_kernel<<<64, 256, 0, stream>>>(coefs);
    hipMemsetAsync(sum1, 0, 2048 * 4, stream);
    hipMemsetAsync(sum2, 0, 16384 * 4, stream);
    init_slots<<<N_, 256, 0, stream>>>(slots, slots + NSQ, cnt, cols, vals, dr);

    int k0 = 0;                        // start of current un-reduced group
    for (int k = 2; k < MUSE_; ++k) {
        cheb_fp16<<<2048, 256, 0, stream>>>(
            slots + (size_t)((k - 1) % g) * NSQ,
            slots + (size_t)((k - 2) % g) * NSQ,
            slots + (size_t)(k % g) * NSQ,
            cnt, cols, vals, dr, perm);
        if (k - k0 + 1 == g || k == MUSE_ - 1) {
            reduce_half<<<2048, 256, 0, stream>>>(slots, g, k0, k - k0 + 1,
                                                  k0 == 0 ? 1 : 0, coefs, Gh);
            k0 = k + 1;
        }
    }
    transpose_f16<<<DF_, 256, 0, stream>>>(f, fhT);
    mfma_gemm0<<<256, 256, 0, stream>>>(Gh, fhT, U1T, sum1);
    gemm256<<<512, 512, 0, stream>>>(Gh, U1T, sum2);
    fmean_kernel<<<DF_, 256, 0, stream>>>(f, out);
    finalize_kernel<<<64, 256, 0, stream>>>(sum1, sum2, out);
}

// Round 17
// 557.029 us; speedup vs baseline: 2.1881x; 1.2433x over previous
//
#include <hip/hip_runtime.h>
#include <hip/hip_fp16.h>
#include <math.h>

// ---------------- constants ----------------
constexpr int   N_   = 2048;
constexpr int   DF_  = 256;
constexpr int   J_   = 8;
constexpr int   ELLW_= 64;
constexpr int   M_   = 256;          // coefficient array stride (256-pt DCT quadrature)
constexpr int   MUSE_= 24;           // Chebyshev terms actually used (degree 23)
constexpr int   GCAP_= 12;           // ring 101MB; exactly 2 reduce passes (12+12)
constexpr float H_   = 1.01f;        // domain half-width  ([-0.01, 2.01])
constexpr float C0_  = 1.0f;         // domain center
constexpr float AF_  = 0.34657359027997264f;   // A = 3*ln(2)/6
constexpr float PI_F = 3.14159265358979323846f;

typedef _Float16 f16x8 __attribute__((ext_vector_type(8)));
typedef __attribute__((ext_vector_type(4))) float f32x4;
using u16 = unsigned short;
typedef __attribute__((address_space(3))) unsigned int lds_u32;
typedef const __attribute__((address_space(1))) unsigned int glb_u32;

// ---------------- filter functions ----------------
__device__ __forceinline__ float g_hat_f(float x) {
    float val = 0.5f + 0.5f * cosf(2.f * PI_F * (x / AF_ + 0.5f));
    return (x <= 0.f && x > -AF_) ? val : 0.f;
}
__device__ __forceinline__ float wavelet_f(float lamb, int j) {
    float lmin = expf(AF_ * ((j - 1) / 3.0f - 1.0f));
    float lam  = fmaxf(lamb, lmin);
    return g_hat_f(logf(lam) - AF_ * (j - 1) / 3.0f);
}
__device__ __forceinline__ float filter_eval(float lamb, int jf) {
    if (jf == 0) {
        float g3 = 0.f;
        for (int j = 2; j <= 8; ++j) { float w = wavelet_f(lamb, j); g3 += w * w; }
        return sqrtf(fmaxf(1.5f - g3, 0.f));
    }
    return wavelet_f(lamb, jf + 1);
}

// ---------------- setup kernels ----------------
__global__ __launch_bounds__(256) void deg_kernel(const float* __restrict__ W,
                                                  float* __restrict__ dh,
                                                  float* __restrict__ dr) {
    int i = blockIdx.x, t = threadIdx.x;
    const float4* row = (const float4*)(W + (size_t)i * N_);
    float s = 0.f;
    for (int c = t; c < N_ / 4; c += 256) { float4 v = row[c]; s += v.x + v.y + v.z + v.w; }
    __shared__ float red[256];
    red[t] = s; __syncthreads();
    for (int o = 128; o; o >>= 1) { if (t < o) red[t] += red[t + o]; __syncthreads(); }
    if (t == 0) {
        float deg = red[0];
        float dhi = 1.f / sqrtf(fmaxf(deg, 1.f));
        dh[i] = dhi;
        dr[i] = (dhi * dhi * deg - C0_) / H_;
    }
}

// ELL build: all 64 entries pre-filled with (col=i, val=0) pads; cnt rounded up to mult of 8.
__global__ __launch_bounds__(64) void ell_kernel(const float* __restrict__ W,
                                                 const float* __restrict__ dh,
                                                 int* __restrict__ cnt,
                                                 int* __restrict__ cols,
                                                 float* __restrict__ vals) {
    int i = blockIdx.x, lane = threadIdx.x;
    cols[i * ELLW_ + lane] = i;            // pad defaults
    vals[i * ELLW_ + lane] = 0.f;
    __syncthreads();
    const float* row = W + (size_t)i * N_;
    unsigned long long lt = (1ull << lane) - 1ull;
    int base = 0;
    float dhi = dh[i];
    for (int c = 0; c < N_; c += 64) {
        float v = row[c + lane];
        unsigned long long m = __ballot(v != 0.f);
        if (v != 0.f) {
            int pos = base + __popcll(m & lt);
            if (pos < ELLW_) {
                cols[i * ELLW_ + pos] = c + lane;
                vals[i * ELLW_ + pos] = dhi * dh[c + lane] / H_;
            }
        }
        base += __popcll(m);
    }
    if (lane == 0) {
        int n = base < ELLW_ ? base : ELLW_;
        cnt[i] = (n + 7) & ~7;             // padded count (pads are no-ops)
    }
}

// deterministic counting sort of rows by padded degree -> perm (parallel scan version)
__global__ __launch_bounds__(256) void perm_kernel(const int* __restrict__ cnt,
                                                   int* __restrict__ perm) {
    __shared__ int hist[9][256];           // per-thread bucket counts -> exclusive offsets
    __shared__ int bstart[9];
    int t = threadIdx.x;
    int b[8];
    int h[9] = {0, 0, 0, 0, 0, 0, 0, 0, 0};
#pragma unroll
    for (int u = 0; u < 8; ++u) {
        b[u] = cnt[t * 8 + u] >> 3;        // bucket 0..8
        h[b[u]]++;
    }
#pragma unroll
    for (int bb = 0; bb < 9; ++bb) hist[bb][t] = h[bb];
    __syncthreads();
    if (t < 9) {                           // exclusive scan across threads, per bucket
        int acc = 0;
        for (int k = 0; k < 256; ++k) { int v = hist[t][k]; hist[t][k] = acc; acc += v; }
        bstart[t] = acc;                   // bucket total
    }
    __syncthreads();
    if (t == 0) {                          // exclusive scan of bucket totals
        int acc = 0;
        for (int bb = 0; bb < 9; ++bb) { int v = bstart[bb]; bstart[bb] = acc; acc += v; }
    }
    __syncthreads();
    int run[9] = {0, 0, 0, 0, 0, 0, 0, 0, 0};
#pragma unroll
    for (int u = 0; u < 8; ++u) {
        int bb = b[u];
        perm[bstart[bb] + hist[bb][t] + run[bb]] = t * 8 + u;
        run[bb]++;
    }
}

// parallel DCT: 64 blocks = 8 filters x 8 output-chunks; 8 threads per output.
__global__ __launch_bounds__(256) void coef_kernel(float* __restrict__ coefs) {
    __shared__ float fv[M_];
    int j     = blockIdx.x >> 3;
    int chunk = blockIdx.x & 7;
    int t = threadIdx.x;
    float theta = PI_F * (t + 0.5f) / M_;
    fv[t] = filter_eval(C0_ + H_ * cosf(theta), j);
    __syncthreads();
    int out = chunk * 32 + (t >> 3);       // output index 0..255
    int seg = t & 7;                       // 8 threads per output
    float s = 0.f;
    for (int i = seg * 32; i < seg * 32 + 32; ++i)
        s += fv[i] * cosf(PI_F * out * (i + 0.5f) / M_);
    s += __shfl_xor(s, 1);
    s += __shfl_xor(s, 2);
    s += __shfl_xor(s, 4);
    if (seg == 0) coefs[j * M_ + out] = s * ((out == 0 ? 1.f : 2.f) / M_);
}

// slot0 = I (fp16), slot1 = scaled L-tilde (fp16)
__global__ __launch_bounds__(256) void init_slots(__half* __restrict__ S0, __half* __restrict__ S1,
                                                  const int* __restrict__ cnt, const int* __restrict__ cols,
                                                  const float* __restrict__ vals, const float* __restrict__ dr) {
    int i = blockIdx.x, t = threadIdx.x;
    size_t ro = (size_t)i * N_;
    for (int c = t * 8; c < N_; c += 2048) {
        *(uint4*)(S0 + ro + c) = uint4{0, 0, 0, 0};
        *(uint4*)(S1 + ro + c) = uint4{0, 0, 0, 0};
    }
    __syncthreads();
    int n = cnt[i];
    if (t < n) {
        int c = cols[i * ELLW_ + t];
        float v = -vals[i * ELLW_ + t];
        if (v != 0.f) S1[ro + c] = __float2half(v);   // skip pads (col=i, val=0)
    }
    __syncthreads();
    if (t == 0) {
        S0[ro + i] = __float2half(1.f);
        S1[ro + i] = __float2half(dr[i]);
    }
}

// ------- Chebyshev step, XCD-striped + degree-sorted rows (proven R8 form: unroll-8) -----
__global__ __launch_bounds__(256) void cheb_fp16(const __half* __restrict__ X,
                                                 const __half* __restrict__ Tprev,
                                                 __half* __restrict__ Tnext,
                                                 const int* __restrict__ cnt,
                                                 const int* __restrict__ cols,
                                                 const float* __restrict__ vals,
                                                 const float* __restrict__ dr,
                                                 const int* __restrict__ perm) {
    int strp = blockIdx.x & 7;
    int rg   = blockIdx.x >> 3;
    int tr   = threadIdx.x >> 5;           // 0..7: row within block
    int lr   = threadIdx.x & 31;
    __shared__ int   sperm[8];
    __shared__ int   scnt[8];
    __shared__ int   scols[8][ELLW_];
    __shared__ float svals[8][ELLW_];
    if (threadIdx.x < 8) {
        int p = perm[rg * 8 + threadIdx.x];
        sperm[threadIdx.x] = p;
        scnt[threadIdx.x]  = cnt[p];
    }
    __syncthreads();
    {
        int e = threadIdx.x & 63, r0 = threadIdx.x >> 6;      // r0 in 0..3
        int p0 = sperm[r0], p1 = sperm[r0 + 4];
        scols[r0][e] = cols[p0 * ELLW_ + e];     svals[r0][e] = vals[p0 * ELLW_ + e];
        scols[r0 + 4][e] = cols[p1 * ELLW_ + e]; svals[r0 + 4][e] = vals[p1 * ELLW_ + e];
    }
    __syncthreads();
    int i   = sperm[tr];
    int n   = scnt[tr];                      // multiple of 8 (or 0)
    int col = strp * 256 + lr * 8;
    float a[8] = {0, 0, 0, 0, 0, 0, 0, 0};
    for (int e0 = 0; e0 < n; e0 += 8) {
        uint4 q[8];
        float v[8];
#pragma unroll
        for (int u = 0; u < 8; ++u) {
            int c = scols[tr][e0 + u];
            v[u] = svals[tr][e0 + u];
            q[u] = *(const uint4*)(X + (size_t)c * N_ + col);
        }
#pragma unroll
        for (int u = 0; u < 8; ++u) {
            const __half2* h = (const __half2*)&q[u];
            float2 f0 = __half22float2(h[0]), f1 = __half22float2(h[1]);
            float2 f2 = __half22float2(h[2]), f3 = __half22float2(h[3]);
            a[0] -= v[u] * f0.x; a[1] -= v[u] * f0.y;
            a[2] -= v[u] * f1.x; a[3] -= v[u] * f1.y;
            a[4] -= v[u] * f2.x; a[5] -= v[u] * f2.y;
            a[6] -= v[u] * f3.x; a[7] -= v[u] * f3.y;
        }
    }
    size_t po = (size_t)i * N_ + col;
    {   // diagonal term
        float d = dr[i];
        uint4 q = *(const uint4*)(X + po);
        const __half2* h = (const __half2*)&q;
        float2 f0 = __half22float2(h[0]), f1 = __half22float2(h[1]);
        float2 f2 = __half22float2(h[2]), f3 = __half22float2(h[3]);
        a[0] += d * f0.x; a[1] += d * f0.y; a[2] += d * f1.x; a[3] += d * f1.y;
        a[4] += d * f2.x; a[5] += d * f2.y; a[6] += d * f3.x; a[7] += d * f3.y;
    }
    uint4 qp = *(const uint4*)(Tprev + po);
    const __half2* hp = (const __half2*)&qp;
    float2 p0 = __half22float2(hp[0]), p1 = __half22float2(hp[1]);
    float2 p2 = __half22float2(hp[2]), p3 = __half22float2(hp[3]);
    __half2 s0 = __floats2half2_rn(2.f * a[0] - p0.x, 2.f * a[1] - p0.y);
    __half2 s1 = __floats2half2_rn(2.f * a[2] - p1.x, 2.f * a[3] - p1.y);
    __half2 s2 = __floats2half2_rn(2.f * a[4] - p2.x, 2.f * a[5] - p2.y);
    __half2 s3 = __floats2half2_rn(2.f * a[6] - p3.x, 2.f * a[7] - p3.y);
    uint4 sq;
    sq.x = *(const unsigned int*)&s0; sq.y = *(const unsigned int*)&s1;
    sq.z = *(const unsigned int*)&s2; sq.w = *(const unsigned int*)&s3;
    *(uint4*)(Tnext + po) = sq;
}

// ---------------- group reduction: Gh_j += sum_{k in [k0,k0+nslot)} b_{jk} * slot(k%g) -------
__global__ __launch_bounds__(256) void reduce_half(const __half* __restrict__ slots,
                                                   int g, int k0, int nslot, int initG,
                                                   const float* __restrict__ coefs,
                                                   __half* __restrict__ Gh) {
    const size_t NSQ = (size_t)N_ * N_;
    size_t idx = ((size_t)blockIdx.x * 256 + threadIdx.x) * 8;
    __shared__ float sc[J_ * 64];
    for (int x = threadIdx.x; x < J_ * nslot; x += 256) {
        int j = x / nslot, s = x - j * nslot;
        sc[j * 64 + s] = coefs[j * M_ + k0 + s];
    }
    __syncthreads();
    float acc[J_][8];
#pragma unroll
    for (int j = 0; j < J_; ++j) {
        if (initG) {
#pragma unroll
            for (int r = 0; r < 8; ++r) acc[j][r] = 0.f;
        } else {
            uint4 q = *(const uint4*)(Gh + (size_t)j * NSQ + idx);
            const __half2* h = (const __half2*)&q;
            float2 f0 = __half22float2(h[0]), f1 = __half22float2(h[1]);
            float2 f2 = __half22float2(h[2]), f3 = __half22float2(h[3]);
            acc[j][0] = f0.x; acc[j][1] = f0.y; acc[j][2] = f1.x; acc[j][3] = f1.y;
            acc[j][4] = f2.x; acc[j][5] = f2.y; acc[j][6] = f3.x; acc[j][7] = f3.y;
        }
    }
    for (int s = 0; s < nslot; ++s) {
        int slot = (k0 + s) % g;
        uint4 q = *(const uint4*)(slots + (size_t)slot * NSQ + idx);
        const __half2* h = (const __half2*)&q;
        float2 f0 = __half22float2(h[0]), f1 = __half22float2(h[1]);
        float2 f2 = __half22float2(h[2]), f3 = __half22float2(h[3]);
        float f[8] = {f0.x, f0.y, f1.x, f1.y, f2.x, f2.y, f3.x, f3.y};
#pragma unroll
        for (int j = 0; j < J_; ++j) {
            float c = sc[j * 64 + s];
#pragma unroll
            for (int r = 0; r < 8; ++r) acc[j][r] += c * f[r];
        }
    }
#pragma unroll
    for (int j = 0; j < J_; ++j) {
        __half2 o0 = __floats2half2_rn(acc[j][0], acc[j][1]);
        __half2 o1 = __floats2half2_rn(acc[j][2], acc[j][3]);
        __half2 o2 = __floats2half2_rn(acc[j][4], acc[j][5]);
        __half2 o3 = __floats2half2_rn(acc[j][6], acc[j][7]);
        uint4 o;
        o.x = *(const unsigned int*)&o0; o.y = *(const unsigned int*)&o1;
        o.z = *(const unsigned int*)&o2; o.w = *(const unsigned int*)&o3;
        *(uint4*)(Gh + (size_t)j * NSQ + idx) = o;
    }
}

// ---------------- f [2048][256] f32  ->  fhT [256][2048] f16 (transposed) ----------------
__global__ __launch_bounds__(256) void transpose_f16(const float* __restrict__ src,
                                                     __half* __restrict__ dst) {
    int d = blockIdx.x;                    // 256 output rows
    int i0 = threadIdx.x * 8;              // 8 nodes per thread
    __half h[8];
#pragma unroll
    for (int u = 0; u < 8; ++u) h[u] = __float2half(src[(size_t)(i0 + u) * DF_ + d]);
    uint4 o;
    __half2* hp = (__half2*)&o;
    hp[0] = __half2{h[0], h[1]}; hp[1] = __half2{h[2], h[3]};
    hp[2] = __half2{h[4], h[5]}; hp[3] = __half2{h[6], h[7]};
    *(uint4*)(dst + (size_t)d * N_ + i0) = o;
}

// ---------------- MODE-0 MFMA GEMM (128x128): U1T = |Gh * fhT^T|, colsum1 ----------------
// 1D grid 256, XCD-chunked; global_load_lds staging (rule #21 involution).
__global__ __launch_bounds__(256) void mfma_gemm0(const __half* __restrict__ A,
                                                  const __half* __restrict__ BT,
                                                  __half* __restrict__ U1T,
                                                  float* __restrict__ colsum) {
    __shared__ u16 As[128 * 64];
    __shared__ u16 Bs[128 * 64];
    int bid = blockIdx.x;
    int xcd = bid & 7, t2 = bid >> 3;      // t2 in 0..31
    int mt  = xcd * 16 + (t2 >> 1);        // m-tile 0..127
    int nt  = t2 & 1;                      // n-tile 0..1
    int tid = threadIdx.x;
    int w = tid >> 6, lane = tid & 63;     // 4 waves, each stages 32 rows
    int wr = w >> 1, wc = w & 1;
    int gm0 = mt * 128, n0 = nt * 128;
    f32x4 acc[4][4];
#pragma unroll
    for (int mf = 0; mf < 4; ++mf)
#pragma unroll
        for (int nf = 0; nf < 4; ++nf) acc[mf][nf] = (f32x4){0.f, 0.f, 0.f, 0.f};

    int lrow = lane >> 3;                  // 0..7
    int gsrc = (lane & 7) ^ lrow;          // inverse-swizzled source granule
    const u16* gaBase = (const u16*)A + (size_t)(gm0 + w * 32 + lrow) * 2048 + gsrc * 8;
    const u16* gbBase = (const u16*)BT + (size_t)(n0 + w * 32 + lrow) * 2048 + gsrc * 8;

    for (int k0 = 0; k0 < 2048; k0 += 64) {
#pragma unroll
        for (int q = 0; q < 4; ++q) {
            const u16* ga = gaBase + (size_t)(q * 8) * 2048 + k0;
            const u16* gb = gbBase + (size_t)(q * 8) * 2048 + k0;
            u16* la = As + (w * 32 + q * 8) * 64;   // wave-uniform LDS base
            u16* lb = Bs + (w * 32 + q * 8) * 64;
            __builtin_amdgcn_global_load_lds((glb_u32*)ga, (lds_u32*)la, 16, 0, 0);
            __builtin_amdgcn_global_load_lds((glb_u32*)gb, (lds_u32*)lb, 16, 0, 0);
        }
        __syncthreads();
#pragma unroll
        for (int s = 0; s < 2; ++s) {
            f16x8 af[4], bfv[4];
#pragma unroll
            for (int mf = 0; mf < 4; ++mf) {
                int row = wr * 64 + mf * 16 + (lane & 15);
                int blk = (s * 4 + (lane >> 4)) ^ (row & 7);
                af[mf] = *(const f16x8*)(As + row * 64 + blk * 8);
            }
#pragma unroll
            for (int nf = 0; nf < 4; ++nf) {
                int row = wc * 64 + nf * 16 + (lane & 15);
                int blk = (s * 4 + (lane >> 4)) ^ (row & 7);
                bfv[nf] = *(const f16x8*)(Bs + row * 64 + blk * 8);
            }
#pragma unroll
            for (int mf = 0; mf < 4; ++mf)
#pragma unroll
                for (int nf = 0; nf < 4; ++nf)
                    acc[mf][nf] = __builtin_amdgcn_mfma_f32_16x16x32_f16(
                        af[mf], bfv[nf], acc[mf][nf], 0, 0, 0);
        }
        __syncthreads();
    }
    int j = gm0 >> 11;
    int ibase = (gm0 & (N_ - 1)) + wr * 64 + (lane >> 4) * 4;
#pragma unroll
    for (int nf = 0; nf < 4; ++nf) {
        int d = n0 + wc * 64 + nf * 16 + (lane & 15);
        float cs = 0.f;
#pragma unroll
        for (int mf = 0; mf < 4; ++mf) {
            float v0 = fabsf(acc[mf][nf][0]);
            float v1 = fabsf(acc[mf][nf][1]);
            float v2 = fabsf(acc[mf][nf][2]);
            float v3 = fabsf(acc[mf][nf][3]);
            cs += v0 + v1 + v2 + v3;
            ushort4 o;
            o.x = __half_as_ushort(__float2half(v0));
            o.y = __half_as_ushort(__float2half(v1));
            o.z = __half_as_ushort(__float2half(v2));
            o.w = __half_as_ushort(__float2half(v3));
            *(ushort4*)(U1T + (size_t)(j * 256 + d) * N_ + ibase + mf * 16) = o;
        }
        cs += __shfl_xor(cs, 16);
        cs += __shfl_xor(cs, 32);
        if ((lane >> 4) == 0) {
            int colg = n0 + wc * 64 + nf * 16 + lane;
            atomicAdd(&colsum[j * 256 + colg], cs);
        }
    }
}

// ---------------- MODE-1 MFMA GEMM (256x256, 512 threads): colsum2 of |Gh * U1T^T| -------
// XCD-chunked + global_load_lds staging (rule #21: linear LDS dest, inverse-swizzled
// global SOURCE, swizzled read).
__global__ __launch_bounds__(512) void gemm256(const __half* __restrict__ A,
                                               const __half* __restrict__ BT,
                                               float* __restrict__ colsum) {
    __shared__ u16 As[256 * 64];
    __shared__ u16 Bs[256 * 64];
    int bid = blockIdx.x;
    int xcd = bid & 7, t2 = bid >> 3;      // t2 in 0..63
    int mt  = xcd * 8 + (t2 >> 3);         // m-tile 0..63
    int nt  = t2 & 7;                      // n-tile 0..7
    int tid = threadIdx.x;
    int w = tid >> 6, lane = tid & 63;
    int wr = w >> 2, wc = w & 3;           // 2 x 4 waves; per-wave tile 128m x 64n
    int gm0 = mt * 256, n0 = nt * 256;
    f32x4 acc[8][4];
#pragma unroll
    for (int mf = 0; mf < 8; ++mf)
#pragma unroll
        for (int nf = 0; nf < 4; ++nf) acc[mf][nf] = (f32x4){0.f, 0.f, 0.f, 0.f};

    int lrow = lane >> 3;                  // 0..7
    int gsrc = (lane & 7) ^ lrow;          // inverse-swizzled source granule
    const u16* gaBase = (const u16*)A + (size_t)(gm0 + w * 32 + lrow) * 2048 + gsrc * 8;
    const u16* gbBase = (const u16*)BT + (size_t)(n0 + w * 32 + lrow) * 2048 + gsrc * 8;

    for (int k0 = 0; k0 < 2048; k0 += 64) {
#pragma unroll
        for (int q = 0; q < 4; ++q) {
            const u16* ga = gaBase + (size_t)(q * 8) * 2048 + k0;
            const u16* gb = gbBase + (size_t)(q * 8) * 2048 + k0;
            u16* la = As + (w * 32 + q * 8) * 64;   // wave-uniform LDS base
            u16* lb = Bs + (w * 32 + q * 8) * 64;
            __builtin_amdgcn_global_load_lds((glb_u32*)ga, (lds_u32*)la, 16, 0, 0);
            __builtin_amdgcn_global_load_lds((glb_u32*)gb, (lds_u32*)lb, 16, 0, 0);
        }
        __syncthreads();
#pragma unroll
        for (int s = 0; s < 2; ++s) {
            f16x8 af[8], bfv[4];
#pragma unroll
            for (int mf = 0; mf < 8; ++mf) {
                int row = wr * 128 + mf * 16 + (lane & 15);
                int blk = (s * 4 + (lane >> 4)) ^ (row & 7);
                af[mf] = *(const f16x8*)(As + row * 64 + blk * 8);
            }
#pragma unroll
            for (int nf = 0; nf < 4; ++nf) {
                int row = wc * 64 + nf * 16 + (lane & 15);
                int blk = (s * 4 + (lane >> 4)) ^ (row & 7);
                bfv[nf] = *(const f16x8*)(Bs + row * 64 + blk * 8);
            }
#pragma unroll
            for (int mf = 0; mf < 8; ++mf)
#pragma unroll
                for (int nf = 0; nf < 4; ++nf)
                    acc[mf][nf] = __builtin_amdgcn_mfma_f32_16x16x32_f16(
                        af[mf], bfv[nf], acc[mf][nf], 0, 0, 0);
        }
        __syncthreads();
    }
    int j = gm0 >> 11;                     // 256-row m-tile never spans a j boundary
#pragma unroll
    for (int nf = 0; nf < 4; ++nf) {
        float cs = 0.f;
#pragma unroll
        for (int mf = 0; mf < 8; ++mf) {
            cs += fabsf(acc[mf][nf][0]) + fabsf(acc[mf][nf][1])
                + fabsf(acc[mf][nf][2]) + fabsf(acc[mf][nf][3]);
        }
        cs += __shfl_xor(cs, 16);
        cs += __shfl_xor(cs, 32);
        if ((lane >> 4) == 0) {
            int colg = n0 + wc * 64 + nf * 16 + lane;
            atomicAdd(&colsum[(((colg >> 8) * 8 + j) << 8) + (colg & 255)], cs);
        }
    }
}

__global__ __launch_bounds__(256) void fmean_kernel(const float* __restrict__ f, float* __restrict__ out) {
    int d = blockIdx.x, t = threadIdx.x;
    float s = 0.f;
    for (int n = t; n < N_; n += 256) s += f[(size_t)n * DF_ + d];
    __shared__ float red[256];
    red[t] = s; __syncthreads();
    for (int o = 128; o; o >>= 1) { if (t < o) red[t] += red[t + o]; __syncthreads(); }
    if (t == 0) out[d] = red[0] * (1.f / N_);
}

__global__ __launch_bounds__(256) void finalize_kernel(const float* __restrict__ sum1,
                                                       const float* __restrict__ sum2,
                                                       float* __restrict__ out) {
    int idx = blockIdx.x * 256 + threadIdx.x;
    if (idx < 2048)  out[256 + idx]  = sum1[idx] * (1.f / N_);
    if (idx < 16384) out[2304 + idx] = sum2[idx] * (1.f / N_);
}

// ---------------- host orchestration ----------------
extern "C" void kernel_launch(void* const* d_in, const int* in_sizes, int n_in,
                              void* d_out, int out_size, void* d_ws, size_t ws_size,
                              hipStream_t stream) {
    (void)in_sizes; (void)n_in;
    const float* W = (const float*)d_in[0];
    const float* f = (const float*)d_in[1];
    float* out = (float*)d_out;
    char* base = (char*)d_ws;
    size_t off = 0;
    auto take = [&](size_t bytes) -> char* {
        off = (off + 255) & ~(size_t)255;
        char* p = base + off; off += bytes; return p;
    };
    const size_t NSQ = (size_t)N_ * N_;
    float*  dh    = (float*)take((size_t)N_ * 4);
    float*  dr    = (float*)take((size_t)N_ * 4);
    int*    cnt   = (int*)take((size_t)N_ * 4);
    int*    perm  = (int*)take((size_t)N_ * 4);
    int*    cols  = (int*)take((size_t)N_ * ELLW_ * 4);
    float*  vals  = (float*)take((size_t)N_ * ELLW_ * 4);
    float*  coefs = (float*)take((size_t)J_ * M_ * 4);
    float*  sum1  = (float*)take(2048 * 4);
    float*  sum2  = (float*)take(16384 * 4);
    __half* Gh    = (__half*)take(NSQ * 2 * J_);                 //  67.1 MB
    __half* U1T   = (__half*)take((size_t)N_ * 2048 * 2);        //   8.4 MB
    __half* fhT   = (__half*)take((size_t)N_ * DF_ * 2);         //   1.0 MB
    off = (off + 255) & ~(size_t)255;
    const size_t slotBytes = NSQ * 2;
    long long rem = (long long)ws_size - (long long)off;
    int g = (int)(rem / (long long)slotBytes);
    if (g > GCAP_) g = GCAP_;
    if (g < 3) {                       // workspace too small — cannot run
        hipMemsetAsync(d_out, 0, (size_t)out_size * 4, stream);
        return;
    }
    __half* slots = (__half*)take((size_t)g * slotBytes);

    deg_kernel<<<N_, 256, 0, stream>>>(W, dh, dr);
    ell_kernel<<<N_, 64, 0, stream>>>(W, dh, cnt, cols, vals);
    perm_kernel<<<1, 256, 0, stream>>>(cnt, perm);
    coef_kernel<<<64, 256, 0, stream>>>(coefs);
    hipMemsetAsync(sum1, 0, 2048 * 4, stream);
    hipMemsetAsync(sum2, 0, 16384 * 4, stream);
    init_slots<<<N_, 256, 0, stream>>>(slots, slots + NSQ, cnt, cols, vals, dr);

    int k0 = 0;                        // start of current un-reduced group
    for (int k = 2; k < MUSE_; ++k) {
        cheb_fp16<<<2048, 256, 0, stream>>>(
            slots + (size_t)((k - 1) % g) * NSQ,
            slots + (size_t)((k - 2) % g) * NSQ,
            slots + (size_t)(k % g) * NSQ,
            cnt, cols, vals, dr, perm);
        if (k - k0 + 1 == g || k == MUSE_ - 1) {
            reduce_half<<<2048, 256, 0, stream>>>(slots, g, k0, k - k0 + 1,
                                                  k0 == 0 ? 1 : 0, coefs, Gh);
            k0 = k + 1;
        }
    }
    transpose_f16<<<DF_, 256, 0, stream>>>(f, fhT);
    mfma_gemm0<<<256, 256, 0, stream>>>(Gh, fhT, U1T, sum1);
    gemm256<<<512, 512, 0, stream>>>(Gh, U1T, sum2);
    fmean_kernel<<<DF_, 256, 0, stream>>>(f, out);
    finalize_kernel<<<64, 256, 0, stream>>>(sum1, sum2, out);
}